// Round 1
// baseline (7529.137 us; speedup 1.0000x reference)
//
#include <hip/hip_runtime.h>
#include <hip/hip_bf16.h>
#include <cstdint>
#include <cstddef>

#define B_   2
#define S_   1024
#define V_   8192
#define D_   1024
#define H_   16
#define KVH_ 4
#define L_   8
#define HD_  64
#define KV_  256
#define HID_ 2736
#define NT_  (B_*S_)
#define EPSF 1.1920928955078125e-7f
#define SOFTCAPF 30.0f

typedef __bf16 bf8 __attribute__((ext_vector_type(8)));
typedef float  f4  __attribute__((ext_vector_type(4)));

// ---------------- wave / block reductions ----------------
__device__ __forceinline__ float wsum(float v){
#pragma unroll
  for (int m = 32; m >= 1; m >>= 1) v += __shfl_xor(v, m, 64);
  return v;
}
__device__ __forceinline__ float wmax(float v){
#pragma unroll
  for (int m = 32; m >= 1; m >>= 1) v = fmaxf(v, __shfl_xor(v, m, 64));
  return v;
}
__device__ __forceinline__ float blocksum256(float v){
  __shared__ float red[4];
  v = wsum(v);
  if ((threadIdx.x & 63) == 0) red[threadIdx.x >> 6] = v;
  __syncthreads();
  return red[0] + red[1] + red[2] + red[3];
}

// ---------------- GEMM: C[M,N] = A[M,K] @ W[N,K]^T (f32 in/out, bf16 MFMA) ----------------
#define LDT 40   // padded LDS row stride in bf16 elems (80 B -> 16B-aligned, 20-bank step)

__device__ __forceinline__ void stage16(const float* src, bool ok, int kbase, int K, __bf16* dst){
  bf8 lo, hi;
#pragma unroll
  for (int jj = 0; jj < 16; jj += 4) {
    float4 v = make_float4(0.f, 0.f, 0.f, 0.f);
    if (ok && (kbase + jj) < K) v = *(const float4*)(src + jj);
    __bf16 b0 = (__bf16)v.x, b1 = (__bf16)v.y, b2 = (__bf16)v.z, b3 = (__bf16)v.w;
    if (jj < 8) { lo[jj] = b0; lo[jj+1] = b1; lo[jj+2] = b2; lo[jj+3] = b3; }
    else        { hi[jj-8] = b0; hi[jj-7] = b1; hi[jj-6] = b2; hi[jj-5] = b3; }
  }
  *(bf8*)dst = lo;
  *(bf8*)(dst + 8) = hi;
}

__global__ __launch_bounds__(256) void k_gemm(
    const float* __restrict__ A, const float* __restrict__ Wt,
    float* __restrict__ C, int M, int N, int K, int mtiles)
{
  __shared__ __attribute__((aligned(16))) __bf16 As[128*LDT];
  __shared__ __attribute__((aligned(16))) __bf16 Bs[128*LDT];
  const int tid  = threadIdx.x;
  const int bm   = blockIdx.x % mtiles;
  const int bn   = blockIdx.x / mtiles;
  const int m0   = bm << 7, n0 = bn << 7;
  const int lane = tid & 63, wv = tid >> 6;
  const int wm   = (wv >> 1) << 6, wn = (wv & 1) << 6;
  const int fr   = lane & 15, ko = (lane >> 4) << 3;

  f4 acc[4][4] = {};

  const int srow = tid >> 1;
  const int sseg = (tid & 1) << 4;
  const float* asrc = A  + (size_t)(m0 + srow) * K + sseg;
  const float* bsrc = Wt + (size_t)(n0 + srow) * K + sseg;
  const bool aok = (m0 + srow) < M;
  const bool bok = (n0 + srow) < N;
  __bf16* adst = &As[srow * LDT + sseg];
  __bf16* bdst = &Bs[srow * LDT + sseg];

  for (int k0 = 0; k0 < K; k0 += 32) {
    __syncthreads();
    stage16(asrc + k0, aok, k0 + sseg, K, adst);
    stage16(bsrc + k0, bok, k0 + sseg, K, bdst);
    __syncthreads();

    bf8 af[4], bff[4];
#pragma unroll
    for (int i = 0; i < 4; ++i) af[i]  = *(const bf8*)&As[(wm + i*16 + fr) * LDT + ko];
#pragma unroll
    for (int j = 0; j < 4; ++j) bff[j] = *(const bf8*)&Bs[(wn + j*16 + fr) * LDT + ko];
#pragma unroll
    for (int i = 0; i < 4; ++i)
#pragma unroll
      for (int j = 0; j < 4; ++j)
        acc[i][j] = __builtin_amdgcn_mfma_f32_16x16x32_bf16(af[i], bff[j], acc[i][j], 0, 0, 0);
  }

  const int rbase = (lane >> 4) << 2;
#pragma unroll
  for (int i = 0; i < 4; ++i) {
    int gm = m0 + wm + i*16 + rbase;
#pragma unroll
    for (int j = 0; j < 4; ++j) {
      int gn = n0 + wn + j*16 + fr;
      if (gn < N) {
#pragma unroll
        for (int r = 0; r < 4; ++r)
          if (gm + r < M) C[(size_t)(gm + r) * N + gn] = acc[i][j][r];
      }
    }
  }
}

// ---------------- embedding + rmsnorm ----------------
__global__ void k_embed(const int* __restrict__ idx, const float* __restrict__ emb,
                        const float* __restrict__ wn, float* __restrict__ x, float* __restrict__ x0)
{
  const int r = blockIdx.x, t = threadIdx.x;
  const float4 v = ((const float4*)(emb + (size_t)idx[r] * D_))[t];
  float ss = blocksum256(v.x*v.x + v.y*v.y + v.z*v.z + v.w*v.w);
  float rs = rsqrtf(ss / (float)D_ + EPSF);
  const float4 w = ((const float4*)wn)[t];
  float4 o = make_float4(v.x*rs*w.x, v.y*rs*w.y, v.z*rs*w.z, v.w*rs*w.w);
  ((float4*)(x  + (size_t)r * D_))[t] = o;
  ((float4*)(x0 + (size_t)r * D_))[t] = o;
}

// ---------------- x = m0*x + m1*x0 ; xn = rmsnorm(x)*nw ----------------
__global__ void k_mixnorm(float* __restrict__ x, const float* __restrict__ x0,
                          const float* __restrict__ mix, const float* __restrict__ nw,
                          float* __restrict__ xn)
{
  const int r = blockIdx.x, t = threadIdx.x;
  float4 xv  = ((float4*)(x + (size_t)r * D_))[t];
  float4 x0v = ((const float4*)(x0 + (size_t)r * D_))[t];
  float4 m0  = ((const float4*)mix)[t];
  float4 m1  = ((const float4*)(mix + D_))[t];
  float4 nv;
  nv.x = m0.x*xv.x + m1.x*x0v.x; nv.y = m0.y*xv.y + m1.y*x0v.y;
  nv.z = m0.z*xv.z + m1.z*x0v.z; nv.w = m0.w*xv.w + m1.w*x0v.w;
  ((float4*)(x + (size_t)r * D_))[t] = nv;
  float ss = blocksum256(nv.x*nv.x + nv.y*nv.y + nv.z*nv.z + nv.w*nv.w);
  float rs = rsqrtf(ss / (float)D_ + EPSF);
  const float4 w = ((const float4*)nw)[t];
  float4 o = make_float4(nv.x*rs*w.x, nv.y*rs*w.y, nv.z*rs*w.z, nv.w*rs*w.w);
  ((float4*)(xn + (size_t)r * D_))[t] = o;
}

// ---------------- generic rmsnorm (C <= 2816) ----------------
__global__ void k_rmsnorm(const float* __restrict__ in, const float* __restrict__ w,
                          float* __restrict__ out, int C)
{
  const int r = blockIdx.x, t = threadIdx.x;
  const float* src = in + (size_t)r * C;
  float vals[11];
  int n = 0; float ss = 0.f;
  for (int c = t; c < C; c += 256) { float v = src[c]; vals[n++] = v; ss += v*v; }
  ss = blocksum256(ss);
  float rs = rsqrtf(ss / (float)C + EPSF);
  n = 0;
  for (int c = t; c < C; c += 256) out[(size_t)r * C + c] = vals[n++] * rs * w[c];
}

// ---------------- dwconv helper ----------------
__device__ __forceinline__ float conv3(const float* buf, int tok, int s, int C, int c, const float* w){
  const float* p0 = buf + (size_t)tok * C + c;
  float a  = (s >= 2) ? p0[-2*C] : 0.f;
  float bb = (s >= 1) ? p0[-C]   : 0.f;
  return w[c]*a + w[C + c]*bb + w[2*C + c]*p0[0];
}

// ---------------- QKV prep: dwconv + head-rmsnorm + RoPE + q_gain ----------------
__global__ __launch_bounds__(1024) void k_prep(
    const float* __restrict__ qlin, const float* __restrict__ klin, const float* __restrict__ vlin,
    const float* __restrict__ qcw, const float* __restrict__ kcw, const float* __restrict__ vcw,
    const float* __restrict__ qgain,
    float* __restrict__ q2, float* __restrict__ k2, float* __restrict__ v2)
{
  const int tok = blockIdx.x;
  const int s = tok & (S_ - 1);
  const int t = threadIdx.x, lane = t & 63;
  __shared__ float qsh[1024];

  // rope tables for this (s, lane)
  const int j = lane & 31;
  float freq = expf(-(float)j * (9.210340371976184f / 32.f));  // 10000^(-j/32)
  float sn, cs;
  sincosf((float)s * freq, &sn, &cs);

  // ---- q ----
  float qc = conv3(qlin, tok, s, D_, t, qcw);
  float ssq = wsum(qc * qc);
  float qn = qc * rsqrtf(ssq / 64.f + EPSF);
  float pr = __shfl_xor(qn, 32, 64);
  float qr = qn * cs + ((lane < 32) ? pr * sn : -pr * sn);
  qsh[t] = qr;
  __syncthreads();
  const int h = t >> 6, hd = lane;
  float accq = 0.f;
#pragma unroll
  for (int g = 0; g < 16; ++g) accq += qgain[h*16 + g] * qsh[g*64 + hd];
  q2[(size_t)tok * D_ + t] = accq;

  // ---- k (threads 0..255) ----
  if (t < 256) {
    float kc = conv3(klin, tok, s, KV_, t, kcw);
    float ssk = wsum(kc * kc);
    float kn = kc * rsqrtf(ssk / 64.f + EPSF);
    float pk = __shfl_xor(kn, 32, 64);
    float kr = kn * cs + ((lane < 32) ? pk * sn : -pk * sn);
    k2[(size_t)tok * KV_ + t] = kr;
  } else if (t < 512) {
    // ---- v (threads 256..511) ----
    int c = t - 256;
    v2[(size_t)tok * KV_ + c] = conv3(vlin, tok, s, KV_, c, vcw);
  }
}

// ---------------- flash attention (f32), 4 q-rows per block ----------------
#define APAD 66
__global__ __launch_bounds__(256) void k_attn(
    const float* __restrict__ q2, const float* __restrict__ k2,
    const float* __restrict__ v2, float* __restrict__ y)
{
  __shared__ float kb[64 * APAD];
  __shared__ float vb[64 * APAD];
  __shared__ float qs[4][64];
  __shared__ float ps[4][64];
  const int id = blockIdx.x;
  const int sg = id & 255;
  const int h  = (id >> 8) & 15;
  const int b  = id >> 12;
  const int tid = threadIdx.x;
  const int lane = tid & 63, wv = tid >> 6;
  const int srow = (sg << 2) + wv;
  const int kvh = h >> 2;

  qs[wv][lane] = q2[(size_t)(b * S_ + srow) * D_ + h * HD_ + lane];

  float m = -1e30f, l = 0.f, o = 0.f;
  const int smax = (sg << 2) + 3;
  const int nch = (smax >> 6) + 1;
  for (int ch = 0; ch < nch; ++ch) {
    const int t0 = ch << 6;
    __syncthreads();
#pragma unroll
    for (int rr = 0; rr < 4; ++rr) {
      int lin = rr * 256 + tid;
      int kr = lin >> 4;
      int sg4 = (lin & 15) << 2;
      size_t gsrc = (size_t)(b * S_ + t0 + kr) * KV_ + kvh * HD_ + sg4;
      float4 kvv = *(const float4*)(k2 + gsrc);
      float4 vvv = *(const float4*)(v2 + gsrc);
      float* kd = &kb[kr * APAD + sg4];
      kd[0] = kvv.x; kd[1] = kvv.y; kd[2] = kvv.z; kd[3] = kvv.w;
      float* vd = &vb[kr * APAD + sg4];
      vd[0] = vvv.x; vd[1] = vvv.y; vd[2] = vvv.z; vd[3] = vvv.w;
    }
    __syncthreads();
    const int tkey = t0 + lane;
    float sc = -1e30f;
    if (tkey <= srow) {
      float d = 0.f;
#pragma unroll
      for (int dd = 0; dd < 64; ++dd) d += qs[wv][dd] * kb[lane * APAD + dd];
      sc = d * 0.125f;
    }
    float mnew = fmaxf(m, wmax(sc));
    float alpha = __expf(m - mnew);
    float pp = __expf(sc - mnew);
    float pl = wsum(pp);
    ps[wv][lane] = pp;
    float oo = o * alpha;
#pragma unroll 8
    for (int tt = 0; tt < 64; ++tt) oo += ps[wv][tt] * vb[tt * APAD + lane];
    o = oo; l = l * alpha + pl; m = mnew;
  }
  y[(size_t)(b * S_ + srow) * D_ + h * HD_ + lane] = o / l;
}

// ---------------- elementwise helpers ----------------
__global__ void k_addscale(float* __restrict__ x, const float* __restrict__ t,
                           const float* __restrict__ sc)
{
  int i = blockIdx.x * 256 + threadIdx.x;      // float4 index over NT*D/4
  int c4 = i & 255;
  float4 xv = ((float4*)x)[i];
  float4 tv = ((const float4*)t)[i];
  float4 s  = ((const float4*)sc)[c4];
  xv.x += s.x * tv.x; xv.y += s.y * tv.y; xv.z += s.z * tv.z; xv.w += s.w * tv.w;
  ((float4*)x)[i] = xv;
}

__global__ void k_skipadd(float* __restrict__ x, const float* __restrict__ sk,
                          const float* __restrict__ sw, const float* __restrict__ sg)
{
  int i = blockIdx.x * 256 + threadIdx.x;
  int c4 = i & 255;
  float4 xv = ((float4*)x)[i];
  float4 sv = ((const float4*)sk)[i];
  float4 w = ((const float4*)sw)[c4];
  float4 g = ((const float4*)sg)[c4];
  xv.x += w.x / (1.f + __expf(-g.x)) * sv.x;
  xv.y += w.y / (1.f + __expf(-g.y)) * sv.y;
  xv.z += w.z / (1.f + __expf(-g.z)) * sv.z;
  xv.w += w.w / (1.f + __expf(-g.w)) * sv.w;
  ((float4*)x)[i] = xv;
}

__global__ void k_copy(float* __restrict__ dst, const float* __restrict__ src){
  int i = blockIdx.x * 256 + threadIdx.x;
  ((float4*)dst)[i] = ((const float4*)src)[i];
}

__global__ void k_silumul(float* __restrict__ h1, const float* __restrict__ h2){
  int i = blockIdx.x * 256 + threadIdx.x;      // float4 over NT*HID/4
  float4 a = ((float4*)h1)[i];
  float4 b = ((const float4*)h2)[i];
  a.x *= b.x / (1.f + __expf(-b.x));
  a.y *= b.y / (1.f + __expf(-b.y));
  a.z *= b.z / (1.f + __expf(-b.z));
  a.w *= b.w / (1.f + __expf(-b.w));
  ((float4*)h1)[i] = a;
}

__global__ void k_dwconv(const float* __restrict__ in, const float* __restrict__ w,
                         float* __restrict__ out, int C)
{
  long i = (long)blockIdx.x * 256 + threadIdx.x;
  if (i >= (long)NT_ * C) return;
  int c = (int)(i % C);
  int row = (int)(i / C);
  int s = row & (S_ - 1);
  float a  = (s >= 2) ? in[i - 2*C] : 0.f;
  float bb = (s >= 1) ? in[i - C]   : 0.f;
  out[i] = w[c]*a + w[C + c]*bb + w[2*C + c]*in[i];
}

__global__ void k_gate(const float* __restrict__ xf, const float* __restrict__ bg,
                       float* __restrict__ gateb)
{
  int r = blockIdx.x * 4 + (threadIdx.x >> 6);
  int lane = threadIdx.x & 63;
  const float* src = xf + (size_t)r * D_;
  float s = 0.f;
#pragma unroll
  for (int c = lane; c < D_; c += 64) s += src[c] * bg[c];
  s = wsum(s);
  if (lane == 0) gateb[r] = 1.f / (1.f + __expf(-s));
}

__global__ void k_final(float* __restrict__ logits, const int* __restrict__ idx,
                        const float* __restrict__ gateb, const float* __restrict__ bh,
                        const float* __restrict__ bsc, const float* __restrict__ ub)
{
  int i = blockIdx.x * 256 + threadIdx.x;      // float4 over NT*V/4
  int row = i >> 11;                            // V/4 = 2048 float4 per row
  int v4 = i & 2047;
  float4 lg = ((float4*)logits)[i];
  float g = gateb[row];
  int tok = idx[row];
  float4 bhv = ((const float4*)(bh + (size_t)tok * V_))[v4];
  float4 bsv = ((const float4*)bsc)[v4];
  float4 ubv = ((const float4*)ub)[v4];
  lg.x = SOFTCAPF * tanhf((lg.x + ubv.x + g * bhv.x * bsv.x) / SOFTCAPF);
  lg.y = SOFTCAPF * tanhf((lg.y + ubv.y + g * bhv.y * bsv.y) / SOFTCAPF);
  lg.z = SOFTCAPF * tanhf((lg.z + ubv.z + g * bhv.z * bsv.z) / SOFTCAPF);
  lg.w = SOFTCAPF * tanhf((lg.w + ubv.w + g * bhv.w * bsv.w) / SOFTCAPF);
  ((float4*)logits)[i] = lg;
}

// ---------------- host ----------------
static inline void gemm(const float* A, const float* W, float* C, int M, int N, int K,
                        hipStream_t s)
{
  int mt = (M + 127) >> 7, nt = (N + 127) >> 7;
  k_gemm<<<dim3(mt * nt), dim3(256), 0, s>>>(A, W, C, M, N, K, mt);
}

extern "C" void kernel_launch(void* const* d_in, const int* in_sizes, int n_in,
                              void* d_out, int out_size, void* d_ws, size_t ws_size,
                              hipStream_t stream)
{
  const int*   idx    = (const int*)d_in[0];
  const float* temb   = (const float*)d_in[1];
  const float* enw    = (const float*)d_in[2];
  const float* rmix   = (const float*)d_in[3];
  const float* anw    = (const float*)d_in[4];
  const float* mnw    = (const float*)d_in[5];
  const float* ascale = (const float*)d_in[6];
  const float* mscale = (const float*)d_in[7];
  const float* Wq     = (const float*)d_in[8];
  const float* Wk     = (const float*)d_in[9];
  const float* Wv     = (const float*)d_in[10];
  const float* qcw    = (const float*)d_in[11];
  const float* kcw    = (const float*)d_in[12];
  const float* vcw    = (const float*)d_in[13];
  const float* qgain  = (const float*)d_in[14];
  const float* panw   = (const float*)d_in[15];
  const float* Wo     = (const float*)d_in[16];
  const float* Wfc    = (const float*)d_in[17];
  const float* Wgate  = (const float*)d_in[18];
  const float* hcw    = (const float*)d_in[19];
  const float* hnw    = (const float*)d_in[20];
  const float* Wmp    = (const float*)d_in[21];
  const float* skw    = (const float*)d_in[22];
  const float* skg    = (const float*)d_in[23];
  const float* fnw    = (const float*)d_in[24];
  const float* lmw    = (const float*)d_in[25];
  const float* bh     = (const float*)d_in[26];
  const float* bsc    = (const float*)d_in[27];
  const float* bg     = (const float*)d_in[28];
  const float* ub     = (const float*)d_in[29];

  float* p = (float*)d_ws;
  float* x    = p; p += (size_t)NT_ * D_;
  float* x0   = p; p += (size_t)NT_ * D_;
  float* xn   = p; p += (size_t)NT_ * D_;
  float* qlin = p; p += (size_t)NT_ * D_;
  float* klin = p; p += (size_t)NT_ * KV_;
  float* vlin = p; p += (size_t)NT_ * KV_;
  float* q2   = p; p += (size_t)NT_ * D_;
  float* k2   = p; p += (size_t)NT_ * KV_;
  float* v2   = p; p += (size_t)NT_ * KV_;
  float* h1   = p; p += (size_t)NT_ * HID_;
  float* h2   = p; p += (size_t)NT_ * HID_;
  float* skips= p; p += (size_t)4 * NT_ * D_;
  float* gateb= p; p += NT_;
  float* logits = (float*)d_out;

  const int g4 = NT_ * D_ / 1024;   // grid for NT*D float4 kernels (=2048)

  k_embed<<<NT_, 256, 0, stream>>>(idx, temb, enw, x, x0);

  for (int i = 0; i < L_; ++i) {
    if (i >= L_/2) {
      int j = i - L_/2;
      k_skipadd<<<g4, 256, 0, stream>>>(x, skips + (size_t)(3 - j) * NT_ * D_,
                                        skw + (size_t)j * D_, skg + (size_t)j * D_);
    }
    // attention
    k_mixnorm<<<NT_, 256, 0, stream>>>(x, x0, rmix + (size_t)i * 2 * D_,
                                       anw + (size_t)i * D_, xn);
    gemm(xn, Wq + (size_t)i * D_ * D_,  qlin, NT_, D_,  D_, stream);
    gemm(xn, Wk + (size_t)i * KV_ * D_, klin, NT_, KV_, D_, stream);
    gemm(xn, Wv + (size_t)i * KV_ * D_, vlin, NT_, KV_, D_, stream);
    k_prep<<<NT_, 1024, 0, stream>>>(qlin, klin, vlin,
                                     qcw + (size_t)i * 3 * D_, kcw + (size_t)i * 3 * KV_,
                                     vcw + (size_t)i * 3 * KV_, qgain + (size_t)i * H_ * H_,
                                     q2, k2, v2);
    k_attn<<<B_ * H_ * (S_/4), 256, 0, stream>>>(q2, k2, v2, qlin);
    k_rmsnorm<<<NT_, 256, 0, stream>>>(qlin, panw + (size_t)i * D_, xn, D_);
    gemm(xn, Wo + (size_t)i * D_ * D_, q2, NT_, D_, D_, stream);
    k_addscale<<<g4, 256, 0, stream>>>(x, q2, ascale + (size_t)i * D_);
    // mlp
    k_rmsnorm<<<NT_, 256, 0, stream>>>(x, mnw + (size_t)i * D_, xn, D_);
    gemm(xn, Wfc   + (size_t)i * HID_ * D_, h1, NT_, HID_, D_, stream);
    gemm(xn, Wgate + (size_t)i * HID_ * D_, h2, NT_, HID_, D_, stream);
    k_silumul<<<NT_ * HID_ / 1024, 256, 0, stream>>>(h1, h2);
    k_dwconv<<<NT_ * HID_ / 256, 256, 0, stream>>>(h1, hcw + (size_t)i * 3 * HID_, h2, HID_);
    k_rmsnorm<<<NT_, 256, 0, stream>>>(h2, hnw + (size_t)i * HID_, h2, HID_);
    gemm(h2, Wmp + (size_t)i * D_ * HID_, qlin, NT_, D_, HID_, stream);
    k_addscale<<<g4, 256, 0, stream>>>(x, qlin, mscale + (size_t)i * D_);

    if (i < L_/2) k_copy<<<g4, 256, 0, stream>>>(skips + (size_t)i * NT_ * D_, x);
  }

  k_rmsnorm<<<NT_, 256, 0, stream>>>(x, fnw, xn, D_);
  gemm(xn, lmw, logits, NT_, V_, D_, stream);
  k_gate<<<NT_/4, 256, 0, stream>>>(xn, bg, gateb);
  k_final<<<NT_ * V_ / 1024, 256, 0, stream>>>(logits, idx, gateb, bh, bsc, ub);
}

// Round 2
// 5184.785 us; speedup vs baseline: 1.4522x; 1.4522x over previous
//
#include <hip/hip_runtime.h>
#include <hip/hip_bf16.h>
#include <cstdint>
#include <cstddef>

#define B_   2
#define S_   1024
#define V_   8192
#define D_   1024
#define H_   16
#define KVH_ 4
#define L_   8
#define HD_  64
#define KV_  256
#define HID_ 2736
#define NT_  (B_*S_)
#define EPSF 1.1920928955078125e-7f
#define SOFTCAPF 30.0f

typedef __bf16 bf8 __attribute__((ext_vector_type(8)));
typedef __bf16 bf4 __attribute__((ext_vector_type(4)));
typedef float  f4  __attribute__((ext_vector_type(4)));

// ---------------- wave / block reductions ----------------
__device__ __forceinline__ float wsum(float v){
#pragma unroll
  for (int m = 32; m >= 1; m >>= 1) v += __shfl_xor(v, m, 64);
  return v;
}
__device__ __forceinline__ float blocksum256(float v){
  __shared__ float red[4];
  v = wsum(v);
  if ((threadIdx.x & 63) == 0) red[threadIdx.x >> 6] = v;
  __syncthreads();
  return red[0] + red[1] + red[2] + red[3];
}

// ---------------- GEMM: C[M,N] = A[M,K] @ W[N,K]^T (f32 in/out, bf16 MFMA) ----------------
#define LDT 40

__device__ __forceinline__ void stage16(const float* src, bool ok, int kbase, int K, __bf16* dst){
  bf8 lo, hi;
#pragma unroll
  for (int jj = 0; jj < 16; jj += 4) {
    float4 v = make_float4(0.f, 0.f, 0.f, 0.f);
    if (ok && (kbase + jj) < K) v = *(const float4*)(src + jj);
    __bf16 b0 = (__bf16)v.x, b1 = (__bf16)v.y, b2 = (__bf16)v.z, b3 = (__bf16)v.w;
    if (jj < 8) { lo[jj] = b0; lo[jj+1] = b1; lo[jj+2] = b2; lo[jj+3] = b3; }
    else        { hi[jj-8] = b0; hi[jj-7] = b1; hi[jj-6] = b2; hi[jj-5] = b3; }
  }
  *(bf8*)dst = lo;
  *(bf8*)(dst + 8) = hi;
}

__global__ __launch_bounds__(256) void k_gemm(
    const float* __restrict__ A, const float* __restrict__ Wt,
    float* __restrict__ C, int M, int N, int K, int mtiles)
{
  __shared__ __attribute__((aligned(16))) __bf16 As[128*LDT];
  __shared__ __attribute__((aligned(16))) __bf16 Bs[128*LDT];
  const int tid  = threadIdx.x;
  const int bm   = blockIdx.x % mtiles;
  const int bn   = blockIdx.x / mtiles;
  const int m0   = bm << 7, n0 = bn << 7;
  const int lane = tid & 63, wv = tid >> 6;
  const int wm   = (wv >> 1) << 6, wn = (wv & 1) << 6;
  const int fr   = lane & 15, ko = (lane >> 4) << 3;

  f4 acc[4][4] = {};

  const int srow = tid >> 1;
  const int sseg = (tid & 1) << 4;
  const float* asrc = A  + (size_t)(m0 + srow) * K + sseg;
  const float* bsrc = Wt + (size_t)(n0 + srow) * K + sseg;
  const bool aok = (m0 + srow) < M;
  const bool bok = (n0 + srow) < N;
  __bf16* adst = &As[srow * LDT + sseg];
  __bf16* bdst = &Bs[srow * LDT + sseg];

  for (int k0 = 0; k0 < K; k0 += 32) {
    __syncthreads();
    stage16(asrc + k0, aok, k0 + sseg, K, adst);
    stage16(bsrc + k0, bok, k0 + sseg, K, bdst);
    __syncthreads();

    bf8 af[4], bff[4];
#pragma unroll
    for (int i = 0; i < 4; ++i) af[i]  = *(const bf8*)&As[(wm + i*16 + fr) * LDT + ko];
#pragma unroll
    for (int j = 0; j < 4; ++j) bff[j] = *(const bf8*)&Bs[(wn + j*16 + fr) * LDT + ko];
#pragma unroll
    for (int i = 0; i < 4; ++i)
#pragma unroll
      for (int j = 0; j < 4; ++j)
        acc[i][j] = __builtin_amdgcn_mfma_f32_16x16x32_bf16(af[i], bff[j], acc[i][j], 0, 0, 0);
  }

  const int rbase = (lane >> 4) << 2;
#pragma unroll
  for (int i = 0; i < 4; ++i) {
    int gm = m0 + wm + i*16 + rbase;
#pragma unroll
    for (int j = 0; j < 4; ++j) {
      int gn = n0 + wn + j*16 + fr;
      if (gn < N) {
#pragma unroll
        for (int r = 0; r < 4; ++r)
          if (gm + r < M) C[(size_t)(gm + r) * N + gn] = acc[i][j][r];
      }
    }
  }
}

// ---------------- embedding + rmsnorm ----------------
__global__ void k_embed(const int* __restrict__ idx, const float* __restrict__ emb,
                        const float* __restrict__ wn, float* __restrict__ x, float* __restrict__ x0)
{
  const int r = blockIdx.x, t = threadIdx.x;
  const float4 v = ((const float4*)(emb + (size_t)idx[r] * D_))[t];
  float ss = blocksum256(v.x*v.x + v.y*v.y + v.z*v.z + v.w*v.w);
  float rs = rsqrtf(ss / (float)D_ + EPSF);
  const float4 w = ((const float4*)wn)[t];
  float4 o = make_float4(v.x*rs*w.x, v.y*rs*w.y, v.z*rs*w.z, v.w*rs*w.w);
  ((float4*)(x  + (size_t)r * D_))[t] = o;
  ((float4*)(x0 + (size_t)r * D_))[t] = o;
}

// ---------------- x = m0*x + m1*x0 ; xn = rmsnorm(x)*nw ----------------
__global__ void k_mixnorm(float* __restrict__ x, const float* __restrict__ x0,
                          const float* __restrict__ mix, const float* __restrict__ nw,
                          float* __restrict__ xn)
{
  const int r = blockIdx.x, t = threadIdx.x;
  float4 xv  = ((float4*)(x + (size_t)r * D_))[t];
  float4 x0v = ((const float4*)(x0 + (size_t)r * D_))[t];
  float4 m0  = ((const float4*)mix)[t];
  float4 m1  = ((const float4*)(mix + D_))[t];
  float4 nv;
  nv.x = m0.x*xv.x + m1.x*x0v.x; nv.y = m0.y*xv.y + m1.y*x0v.y;
  nv.z = m0.z*xv.z + m1.z*x0v.z; nv.w = m0.w*xv.w + m1.w*x0v.w;
  ((float4*)(x + (size_t)r * D_))[t] = nv;
  float ss = blocksum256(nv.x*nv.x + nv.y*nv.y + nv.z*nv.z + nv.w*nv.w);
  float rs = rsqrtf(ss / (float)D_ + EPSF);
  const float4 w = ((const float4*)nw)[t];
  float4 o = make_float4(nv.x*rs*w.x, nv.y*rs*w.y, nv.z*rs*w.z, nv.w*rs*w.w);
  ((float4*)(xn + (size_t)r * D_))[t] = o;
}

// ---------------- generic rmsnorm (C <= 2816) ----------------
__global__ void k_rmsnorm(const float* __restrict__ in, const float* __restrict__ w,
                          float* __restrict__ out, int C)
{
  const int r = blockIdx.x, t = threadIdx.x;
  const float* src = in + (size_t)r * C;
  float vals[11];
  int n = 0; float ss = 0.f;
  for (int c = t; c < C; c += 256) { float v = src[c]; vals[n++] = v; ss += v*v; }
  ss = blocksum256(ss);
  float rs = rsqrtf(ss / (float)C + EPSF);
  n = 0;
  for (int c = t; c < C; c += 256) out[(size_t)r * C + c] = vals[n++] * rs * w[c];
}

// ---------------- dwconv helper ----------------
__device__ __forceinline__ float conv3(const float* buf, int tok, int s, int C, int c, const float* w){
  const float* p0 = buf + (size_t)tok * C + c;
  float a  = (s >= 2) ? p0[-2*C] : 0.f;
  float bb = (s >= 1) ? p0[-C]   : 0.f;
  return w[c]*a + w[C + c]*bb + w[2*C + c]*p0[0];
}

// ---------------- QKV prep: dwconv + head-rmsnorm + RoPE + q_gain -> bf16 ----------------
__global__ __launch_bounds__(1024) void k_prep(
    const float* __restrict__ qlin, const float* __restrict__ klin, const float* __restrict__ vlin,
    const float* __restrict__ qcw, const float* __restrict__ kcw, const float* __restrict__ vcw,
    const float* __restrict__ qgain,
    __bf16* __restrict__ q2, __bf16* __restrict__ k2, __bf16* __restrict__ v2)
{
  const int tok = blockIdx.x;
  const int s = tok & (S_ - 1);
  const int t = threadIdx.x, lane = t & 63;
  __shared__ float qsh[1024];

  const int j = lane & 31;
  float freq = expf(-(float)j * (9.210340371976184f / 32.f));
  float sn, cs;
  sincosf((float)s * freq, &sn, &cs);

  // ---- q ----
  float qc = conv3(qlin, tok, s, D_, t, qcw);
  float ssq = wsum(qc * qc);
  float qn = qc * rsqrtf(ssq / 64.f + EPSF);
  float pr = __shfl_xor(qn, 32, 64);
  float qr = qn * cs + ((lane < 32) ? pr * sn : -pr * sn);
  qsh[t] = qr;
  __syncthreads();
  const int h = t >> 6, hd = lane;
  float accq = 0.f;
#pragma unroll
  for (int g = 0; g < 16; ++g) accq += qgain[h*16 + g] * qsh[g*64 + hd];
  q2[(size_t)tok * D_ + t] = (__bf16)accq;

  if (t < 256) {
    float kc = conv3(klin, tok, s, KV_, t, kcw);
    float ssk = wsum(kc * kc);
    float kn = kc * rsqrtf(ssk / 64.f + EPSF);
    float pk = __shfl_xor(kn, 32, 64);
    float kr = kn * cs + ((lane < 32) ? pk * sn : -pk * sn);
    k2[(size_t)tok * KV_ + t] = (__bf16)kr;
  } else if (t < 512) {
    int c = t - 256;
    v2[(size_t)tok * KV_ + c] = (__bf16)conv3(vlin, tok, s, KV_, c, vcw);
  }
}

// ---------------- MFMA flash attention (bf16 compute, f32 accumulate) ----------------
// Block: 64 q rows of one (b,h); 4 waves x 16 q rows. K-chunks of 64 keys.
// S^T = K.Q^T  (lane owns q = lane&15 -> lane-local softmax state)
// O^T = V^T.P^T (accumulator also q = lane&15 local)
#define LDK 72
__global__ __launch_bounds__(256) void k_attn(
    const __bf16* __restrict__ q2, const __bf16* __restrict__ k2,
    const __bf16* __restrict__ v2, float* __restrict__ y)
{
  __shared__ __attribute__((aligned(16))) __bf16 Ks[64*LDK];
  __shared__ __attribute__((aligned(16))) __bf16 Vt[64*LDK];
  __shared__ __attribute__((aligned(16))) __bf16 Ps[4][16*LDK];

  const int id = blockIdx.x;
  const int qb = id & 15;          // q tile (S/64)
  const int h  = (id >> 4) & 15;
  const int b  = id >> 8;
  const int tid = threadIdx.x, l = tid & 63, wq = tid >> 6;
  const int g = l >> 4, fr = l & 15;
  const int kvh = h >> 2;
  const int qrow = qb*64 + wq*16 + fr;   // this lane's q row (sequence pos)

  bf8 qf[2];
#pragma unroll
  for (int ks = 0; ks < 2; ++ks)
    qf[ks] = *(const bf8*)&q2[(size_t)(b*S_ + qrow)*D_ + h*64 + g*8 + ks*32];

  float m = -1e30f, lsum = 0.f;
  f4 acc[4] = {};

  const int nch = qb + 1;
  for (int ch = 0; ch < nch; ++ch) {
    const int t0 = ch << 6;
    __syncthreads();
    // ---- stage K row-major ----
#pragma unroll
    for (int it = 0; it < 2; ++it) {
      int i = tid + it*256;
      int row = i >> 3, seg = (i & 7) << 3;
      *(bf8*)&Ks[row*LDK + seg] =
        *(const bf8*)&k2[(size_t)(b*S_ + t0 + row)*KV_ + kvh*64 + seg];
    }
    // ---- stage V transposed (4key x 4hd per thread) ----
    {
      int key4 = (tid & 15) << 2, hd4 = (tid >> 4) << 2;
      bf4 vv[4];
#pragma unroll
      for (int kk = 0; kk < 4; ++kk)
        vv[kk] = *(const bf4*)&v2[(size_t)(b*S_ + t0 + key4 + kk)*KV_ + kvh*64 + hd4];
#pragma unroll
      for (int hh = 0; hh < 4; ++hh) {
        bf4 w = { vv[0][hh], vv[1][hh], vv[2][hh], vv[3][hh] };
        *(bf4*)&Vt[(hd4 + hh)*LDK + key4] = w;
      }
    }
    __syncthreads();

    // ---- S^T = K . Q^T ----
    f4 sc[4] = {};
#pragma unroll
    for (int ks = 0; ks < 2; ++ks)
#pragma unroll
      for (int t = 0; t < 4; ++t) {
        bf8 kf = *(const bf8*)&Ks[(t*16 + fr)*LDK + g*8 + ks*32];
        sc[t] = __builtin_amdgcn_mfma_f32_16x16x32_bf16(kf, qf[ks], sc[t], 0, 0, 0);
      }

    // ---- online softmax (lane-local per q) ----
    const bool lastch = (ch == qb);
    float s[4][4];
    float pmax = -1e30f;
#pragma unroll
    for (int t = 0; t < 4; ++t)
#pragma unroll
      for (int r = 0; r < 4; ++r) {
        float v = sc[t][r] * 0.125f;
        if (lastch && (t0 + t*16 + g*4 + r > qrow)) v = -1e30f;
        s[t][r] = v;
        pmax = fmaxf(pmax, v);
      }
    pmax = fmaxf(pmax, __shfl_xor(pmax, 16, 64));
    pmax = fmaxf(pmax, __shfl_xor(pmax, 32, 64));
    float mnew = fmaxf(m, pmax);
    float alpha = __expf(m - mnew);
    float rs = 0.f;
#pragma unroll
    for (int t = 0; t < 4; ++t)
#pragma unroll
      for (int r = 0; r < 4; ++r) { float p = __expf(s[t][r] - mnew); s[t][r] = p; rs += p; }
    rs += __shfl_xor(rs, 16, 64);
    rs += __shfl_xor(rs, 32, 64);
    lsum = lsum * alpha + rs;
    m = mnew;
#pragma unroll
    for (int t = 0; t < 4; ++t) acc[t] = acc[t] * alpha;

    // ---- pack P -> per-wave LDS (q row-major) ----
#pragma unroll
    for (int t = 0; t < 4; ++t) {
      bf4 pw = { (__bf16)s[t][0], (__bf16)s[t][1], (__bf16)s[t][2], (__bf16)s[t][3] };
      *(bf4*)&Ps[wq][fr*LDK + t*16 + g*4] = pw;
    }

    // ---- O^T += V^T . P^T ----
#pragma unroll
    for (int ks = 0; ks < 2; ++ks) {
      bf8 pf = *(const bf8*)&Ps[wq][fr*LDK + g*8 + ks*32];
#pragma unroll
      for (int t = 0; t < 4; ++t) {
        bf8 vf = *(const bf8*)&Vt[(t*16 + fr)*LDK + g*8 + ks*32];
        acc[t] = __builtin_amdgcn_mfma_f32_16x16x32_bf16(vf, pf, acc[t], 0, 0, 0);
      }
    }
  }

  float inv = 1.f / lsum;
#pragma unroll
  for (int t = 0; t < 4; ++t)
#pragma unroll
    for (int r = 0; r < 4; ++r)
      y[(size_t)(b*S_ + qrow)*D_ + h*64 + t*16 + g*4 + r] = acc[t][r] * inv;
}

// ---------------- elementwise helpers ----------------
__global__ void k_addscale(float* __restrict__ x, const float* __restrict__ t,
                           const float* __restrict__ sc)
{
  int i = blockIdx.x * 256 + threadIdx.x;
  int c4 = i & 255;
  float4 xv = ((float4*)x)[i];
  float4 tv = ((const float4*)t)[i];
  float4 s  = ((const float4*)sc)[c4];
  xv.x += s.x * tv.x; xv.y += s.y * tv.y; xv.z += s.z * tv.z; xv.w += s.w * tv.w;
  ((float4*)x)[i] = xv;
}

__global__ void k_skipadd(float* __restrict__ x, const float* __restrict__ sk,
                          const float* __restrict__ sw, const float* __restrict__ sg)
{
  int i = blockIdx.x * 256 + threadIdx.x;
  int c4 = i & 255;
  float4 xv = ((float4*)x)[i];
  float4 sv = ((const float4*)sk)[i];
  float4 w = ((const float4*)sw)[c4];
  float4 g = ((const float4*)sg)[c4];
  xv.x += w.x / (1.f + __expf(-g.x)) * sv.x;
  xv.y += w.y / (1.f + __expf(-g.y)) * sv.y;
  xv.z += w.z / (1.f + __expf(-g.z)) * sv.z;
  xv.w += w.w / (1.f + __expf(-g.w)) * sv.w;
  ((float4*)x)[i] = xv;
}

__global__ void k_copy(float* __restrict__ dst, const float* __restrict__ src){
  int i = blockIdx.x * 256 + threadIdx.x;
  ((float4*)dst)[i] = ((const float4*)src)[i];
}

__global__ void k_silumul(float* __restrict__ h1, const float* __restrict__ h2){
  int i = blockIdx.x * 256 + threadIdx.x;
  float4 a = ((float4*)h1)[i];
  float4 b = ((const float4*)h2)[i];
  a.x *= b.x / (1.f + __expf(-b.x));
  a.y *= b.y / (1.f + __expf(-b.y));
  a.z *= b.z / (1.f + __expf(-b.z));
  a.w *= b.w / (1.f + __expf(-b.w));
  ((float4*)h1)[i] = a;
}

__global__ void k_dwconv(const float* __restrict__ in, const float* __restrict__ w,
                         float* __restrict__ out, int C)
{
  long i = (long)blockIdx.x * 256 + threadIdx.x;
  if (i >= (long)NT_ * C) return;
  int c = (int)(i % C);
  int row = (int)(i / C);
  int s = row & (S_ - 1);
  float a  = (s >= 2) ? in[i - 2*C] : 0.f;
  float bb = (s >= 1) ? in[i - C]   : 0.f;
  out[i] = w[c]*a + w[C + c]*bb + w[2*C + c]*in[i];
}

__global__ void k_gate(const float* __restrict__ xf, const float* __restrict__ bg,
                       float* __restrict__ gateb)
{
  int r = blockIdx.x * 4 + (threadIdx.x >> 6);
  int lane = threadIdx.x & 63;
  const float* src = xf + (size_t)r * D_;
  float s = 0.f;
#pragma unroll
  for (int c = lane; c < D_; c += 64) s += src[c] * bg[c];
  s = wsum(s);
  if (lane == 0) gateb[r] = 1.f / (1.f + __expf(-s));
}

__global__ void k_final(float* __restrict__ logits, const int* __restrict__ idx,
                        const float* __restrict__ gateb, const float* __restrict__ bh,
                        const float* __restrict__ bsc, const float* __restrict__ ub)
{
  int i = blockIdx.x * 256 + threadIdx.x;
  int row = i >> 11;
  int v4 = i & 2047;
  float4 lg = ((float4*)logits)[i];
  float g = gateb[row];
  int tok = idx[row];
  float4 bhv = ((const float4*)(bh + (size_t)tok * V_))[v4];
  float4 bsv = ((const float4*)bsc)[v4];
  float4 ubv = ((const float4*)ub)[v4];
  lg.x = SOFTCAPF * tanhf((lg.x + ubv.x + g * bhv.x * bsv.x) / SOFTCAPF);
  lg.y = SOFTCAPF * tanhf((lg.y + ubv.y + g * bhv.y * bsv.y) / SOFTCAPF);
  lg.z = SOFTCAPF * tanhf((lg.z + ubv.z + g * bhv.z * bsv.z) / SOFTCAPF);
  lg.w = SOFTCAPF * tanhf((lg.w + ubv.w + g * bhv.w * bsv.w) / SOFTCAPF);
  ((float4*)logits)[i] = lg;
}

// ---------------- host ----------------
static inline void gemm(const float* A, const float* W, float* C, int M, int N, int K,
                        hipStream_t s)
{
  int mt = (M + 127) >> 7, nt = (N + 127) >> 7;
  k_gemm<<<dim3(mt * nt), dim3(256), 0, s>>>(A, W, C, M, N, K, mt);
}

extern "C" void kernel_launch(void* const* d_in, const int* in_sizes, int n_in,
                              void* d_out, int out_size, void* d_ws, size_t ws_size,
                              hipStream_t stream)
{
  const int*   idx    = (const int*)d_in[0];
  const float* temb   = (const float*)d_in[1];
  const float* enw    = (const float*)d_in[2];
  const float* rmix   = (const float*)d_in[3];
  const float* anw    = (const float*)d_in[4];
  const float* mnw    = (const float*)d_in[5];
  const float* ascale = (const float*)d_in[6];
  const float* mscale = (const float*)d_in[7];
  const float* Wq     = (const float*)d_in[8];
  const float* Wk     = (const float*)d_in[9];
  const float* Wv     = (const float*)d_in[10];
  const float* qcw    = (const float*)d_in[11];
  const float* kcw    = (const float*)d_in[12];
  const float* vcw    = (const float*)d_in[13];
  const float* qgain  = (const float*)d_in[14];
  const float* panw   = (const float*)d_in[15];
  const float* Wo     = (const float*)d_in[16];
  const float* Wfc    = (const float*)d_in[17];
  const float* Wgate  = (const float*)d_in[18];
  const float* hcw    = (const float*)d_in[19];
  const float* hnw    = (const float*)d_in[20];
  const float* Wmp    = (const float*)d_in[21];
  const float* skw    = (const float*)d_in[22];
  const float* skg    = (const float*)d_in[23];
  const float* fnw    = (const float*)d_in[24];
  const float* lmw    = (const float*)d_in[25];
  const float* bh     = (const float*)d_in[26];
  const float* bsc    = (const float*)d_in[27];
  const float* bg     = (const float*)d_in[28];
  const float* ub     = (const float*)d_in[29];

  float* p = (float*)d_ws;
  float* x    = p; p += (size_t)NT_ * D_;
  float* x0   = p; p += (size_t)NT_ * D_;
  float* xn   = p; p += (size_t)NT_ * D_;
  float* qlin = p; p += (size_t)NT_ * D_;
  float* klin = p; p += (size_t)NT_ * KV_;
  float* vlin = p; p += (size_t)NT_ * KV_;
  // bf16 region (reuses what used to be f32 q2/k2/v2): NT*D + 2*NT*KV bf16
  __bf16* q2b = (__bf16*)p; p += (size_t)NT_ * D_ / 2;
  __bf16* k2b = (__bf16*)p; p += (size_t)NT_ * KV_ / 2;
  __bf16* v2b = (__bf16*)p; p += (size_t)NT_ * KV_ / 2;
  float* h1   = p; p += (size_t)NT_ * HID_;
  float* h2   = p; p += (size_t)NT_ * HID_;
  float* skips= p; p += (size_t)4 * NT_ * D_;
  float* gateb= p; p += NT_;
  float* logits = (float*)d_out;

  const int g4 = NT_ * D_ / 1024;

  k_embed<<<NT_, 256, 0, stream>>>(idx, temb, enw, x, x0);

  for (int i = 0; i < L_; ++i) {
    if (i >= L_/2) {
      int j = i - L_/2;
      k_skipadd<<<g4, 256, 0, stream>>>(x, skips + (size_t)(3 - j) * NT_ * D_,
                                        skw + (size_t)j * D_, skg + (size_t)j * D_);
    }
    // attention
    k_mixnorm<<<NT_, 256, 0, stream>>>(x, x0, rmix + (size_t)i * 2 * D_,
                                       anw + (size_t)i * D_, xn);
    gemm(xn, Wq + (size_t)i * D_ * D_,  qlin, NT_, D_,  D_, stream);
    gemm(xn, Wk + (size_t)i * KV_ * D_, klin, NT_, KV_, D_, stream);
    gemm(xn, Wv + (size_t)i * KV_ * D_, vlin, NT_, KV_, D_, stream);
    k_prep<<<NT_, 1024, 0, stream>>>(qlin, klin, vlin,
                                     qcw + (size_t)i * 3 * D_, kcw + (size_t)i * 3 * KV_,
                                     vcw + (size_t)i * 3 * KV_, qgain + (size_t)i * H_ * H_,
                                     q2b, k2b, v2b);
    k_attn<<<B_ * H_ * (S_/64), 256, 0, stream>>>(q2b, k2b, v2b, qlin);
    k_rmsnorm<<<NT_, 256, 0, stream>>>(qlin, panw + (size_t)i * D_, xn, D_);
    gemm(xn, Wo + (size_t)i * D_ * D_, h1, NT_, D_, D_, stream);
    k_addscale<<<g4, 256, 0, stream>>>(x, h1, ascale + (size_t)i * D_);
    // mlp
    k_rmsnorm<<<NT_, 256, 0, stream>>>(x, mnw + (size_t)i * D_, xn, D_);
    gemm(xn, Wfc   + (size_t)i * HID_ * D_, h1, NT_, HID_, D_, stream);
    gemm(xn, Wgate + (size_t)i * HID_ * D_, h2, NT_, HID_, D_, stream);
    k_silumul<<<NT_ * HID_ / 1024, 256, 0, stream>>>(h1, h2);
    k_dwconv<<<NT_ * HID_ / 256, 256, 0, stream>>>(h1, hcw + (size_t)i * 3 * HID_, h2, HID_);
    k_rmsnorm<<<NT_, 256, 0, stream>>>(h2, hnw + (size_t)i * HID_, h2, HID_);
    gemm(h2, Wmp + (size_t)i * D_ * HID_, qlin, NT_, D_, HID_, stream);
    k_addscale<<<g4, 256, 0, stream>>>(x, qlin, mscale + (size_t)i * D_);

    if (i < L_/2) k_copy<<<g4, 256, 0, stream>>>(skips + (size_t)i * NT_ * D_, x);
  }

  k_rmsnorm<<<NT_, 256, 0, stream>>>(x, fnw, xn, D_);
  gemm(xn, lmw, logits, NT_, V_, D_, stream);
  k_gate<<<NT_/4, 256, 0, stream>>>(xn, bg, gateb);
  k_final<<<NT_ * V_ / 1024, 256, 0, stream>>>(logits, idx, gateb, bh, bsc, ub);
}

// Round 3
// 2419.592 us; speedup vs baseline: 3.1117x; 2.1428x over previous
//
#include <hip/hip_runtime.h>
#include <hip/hip_bf16.h>
#include <cstdint>
#include <cstddef>

#define B_   2
#define S_   1024
#define V_   8192
#define D_   1024
#define H_   16
#define KVH_ 4
#define L_   8
#define HD_  64
#define KV_  256
#define HID_ 2736
#define HIDP 2752
#define NT_  (B_*S_)
#define EPSF 1.1920928955078125e-7f
#define SOFTCAPF 30.0f

typedef __bf16 bf8 __attribute__((ext_vector_type(8)));
typedef __bf16 bf4 __attribute__((ext_vector_type(4)));
typedef float  f4  __attribute__((ext_vector_type(4)));

// async global->LDS, 16B per lane; dst is wave-uniform base + lane*16
#define GLDS16(g, l) __builtin_amdgcn_global_load_lds( \
    (const __attribute__((address_space(1))) void*)(g), \
    (__attribute__((address_space(3))) void*)(l), 16, 0, 0)

// ---------------- wave / block reductions ----------------
__device__ __forceinline__ float wsum(float v){
#pragma unroll
  for (int m = 32; m >= 1; m >>= 1) v += __shfl_xor(v, m, 64);
  return v;
}
__device__ __forceinline__ float blocksum256(float v){
  __shared__ float red[4];
  v = wsum(v);
  if ((threadIdx.x & 63) == 0) red[threadIdx.x >> 6] = v;
  __syncthreads();
  return red[0] + red[1] + red[2] + red[3];
}

// ---------------- GEMM: C[M,N] = A[M,K] @ W[N,K]^T (bf16 in, f32 out) ----------------
// m97 structure: 128x128 tile, BK=32, global_load_lds width 16, 4 waves.
// LDS linear [128][32] bf16; col-segment XOR swizzle (seg' = seg ^ (row&3)) applied
// on the GLOBAL source address (write side) and on the ds_read (read side).
__global__ __launch_bounds__(256) void k_gemm(
    const __bf16* __restrict__ A, const __bf16* __restrict__ Wt,
    float* __restrict__ C, int M, int N, int K, int lda, int mtiles)
{
  __shared__ __attribute__((aligned(16))) __bf16 As[128*32];
  __shared__ __attribute__((aligned(16))) __bf16 Bs[128*32];
  const int tid  = threadIdx.x;
  const int bm   = blockIdx.x % mtiles;
  const int bn   = blockIdx.x / mtiles;
  const int m0   = bm << 7, n0 = bn << 7;
  const int lane = tid & 63, wv = tid >> 6;
  const int wm   = (wv >> 1) << 6, wn = (wv & 1) << 6;
  const int fr   = lane & 15, g = lane >> 4;

  f4 acc[4][4] = {};

  // staging: per wave, 2 issues for A (rows wv*32..wv*32+31) and 2 for B
  const int r0 = lane >> 2;
  const int cs = (lane & 3) ^ (r0 & 3);          // swizzled 8-elem col segment
  const __bf16* aq0 = A + (size_t)(m0 + wv*32 + r0) * lda + cs*8;
  const __bf16* aq1 = aq0 + (size_t)16 * lda;
  int br0 = n0 + wv*32 + r0;      if (br0 > N-1) br0 = N-1;
  int br1 = n0 + wv*32 + r0 + 16; if (br1 > N-1) br1 = N-1;
  const __bf16* bq0 = Wt + (size_t)br0 * K + cs*8;
  const __bf16* bq1 = Wt + (size_t)br1 * K + cs*8;
  __bf16* al0 = As + wv*1024;  __bf16* al1 = al0 + 512;
  __bf16* bl0 = Bs + wv*1024;  __bf16* bl1 = bl0 + 512;

  for (int k0 = 0; k0 < K; k0 += 32) {
    __syncthreads();
    GLDS16(aq0, al0); GLDS16(aq1, al1);
    GLDS16(bq0, bl0); GLDS16(bq1, bl1);
    aq0 += 32; aq1 += 32; bq0 += 32; bq1 += 32;
    __syncthreads();   // drains vmcnt -> LDS tile complete

    bf8 af[4], bff[4];
#pragma unroll
    for (int i = 0; i < 4; ++i)
      af[i]  = *(const bf8*)&As[(wm + i*16 + fr) * 32 + ((g ^ (fr & 3)) << 3)];
#pragma unroll
    for (int j = 0; j < 4; ++j)
      bff[j] = *(const bf8*)&Bs[(wn + j*16 + fr) * 32 + ((g ^ (fr & 3)) << 3)];
#pragma unroll
    for (int i = 0; i < 4; ++i)
#pragma unroll
      for (int j = 0; j < 4; ++j)
        acc[i][j] = __builtin_amdgcn_mfma_f32_16x16x32_bf16(af[i], bff[j], acc[i][j], 0, 0, 0);
  }

  const int rbase = g << 2;
#pragma unroll
  for (int i = 0; i < 4; ++i) {
    int gm = m0 + wm + i*16 + rbase;
#pragma unroll
    for (int j = 0; j < 4; ++j) {
      int gn = n0 + wn + j*16 + fr;
      if (gn < N) {
#pragma unroll
        for (int r = 0; r < 4; ++r)
          C[(size_t)(gm + r) * N + gn] = acc[i][j][r];
      }
    }
  }
}

// ---------------- weight f32 -> bf16 convert (with layer interleave + K pad) ----------------
__global__ void k_cvt(const float* __restrict__ s, __bf16* __restrict__ d,
                      int perL, int K, int Kpad, long dstL, long dstOff, long nd4)
{
  long i = (long)blockIdx.x * 256 + threadIdx.x;
  if (i >= nd4) return;
  const int kp4 = Kpad >> 2;
  long row = i / kp4;
  int  c   = (int)(i % kp4) << 2;
  long layer = row / perL, r = row % perL;
  bf4 o;
  if (c < K) {
    float4 v = *(const float4*)(s + (layer*perL + r) * (long)K + c);
    o[0] = (__bf16)v.x; o[1] = (__bf16)v.y; o[2] = (__bf16)v.z; o[3] = (__bf16)v.w;
  } else { o[0] = o[1] = o[2] = o[3] = (__bf16)0.f; }
  *(bf4*)(d + layer*dstL + dstOff + (long)r*Kpad + c) = o;
}

// ---------------- embedding + rmsnorm ----------------
__global__ void k_embed(const int* __restrict__ idx, const float* __restrict__ emb,
                        const float* __restrict__ wn, float* __restrict__ x, float* __restrict__ x0)
{
  const int r = blockIdx.x, t = threadIdx.x;
  const float4 v = ((const float4*)(emb + (size_t)idx[r] * D_))[t];
  float ss = blocksum256(v.x*v.x + v.y*v.y + v.z*v.z + v.w*v.w);
  float rs = rsqrtf(ss / (float)D_ + EPSF);
  const float4 w = ((const float4*)wn)[t];
  float4 o = make_float4(v.x*rs*w.x, v.y*rs*w.y, v.z*rs*w.z, v.w*rs*w.w);
  ((float4*)(x  + (size_t)r * D_))[t] = o;
  ((float4*)(x0 + (size_t)r * D_))[t] = o;
}

// ---------------- x = m0*x + m1*x0 ; xn = bf16(rmsnorm(x)*nw) ----------------
__global__ void k_mixnorm(float* __restrict__ x, const float* __restrict__ x0,
                          const float* __restrict__ mix, const float* __restrict__ nw,
                          __bf16* __restrict__ xn)
{
  const int r = blockIdx.x, t = threadIdx.x;
  float4 xv  = ((float4*)(x + (size_t)r * D_))[t];
  float4 x0v = ((const float4*)(x0 + (size_t)r * D_))[t];
  float4 m0  = ((const float4*)mix)[t];
  float4 m1  = ((const float4*)(mix + D_))[t];
  float4 nv;
  nv.x = m0.x*xv.x + m1.x*x0v.x; nv.y = m0.y*xv.y + m1.y*x0v.y;
  nv.z = m0.z*xv.z + m1.z*x0v.z; nv.w = m0.w*xv.w + m1.w*x0v.w;
  ((float4*)(x + (size_t)r * D_))[t] = nv;
  float ss = blocksum256(nv.x*nv.x + nv.y*nv.y + nv.z*nv.z + nv.w*nv.w);
  float rs = rsqrtf(ss / (float)D_ + EPSF);
  const float4 w = ((const float4*)nw)[t];
  bf4 o = { (__bf16)(nv.x*rs*w.x), (__bf16)(nv.y*rs*w.y),
            (__bf16)(nv.z*rs*w.z), (__bf16)(nv.w*rs*w.w) };
  ((bf4*)(xn + (size_t)r * D_))[t] = o;
}

// ---------------- rmsnorm D=1024, f32 in -> bf16 out ----------------
__global__ void k_rmsnormb(const float* __restrict__ in, const float* __restrict__ w,
                           __bf16* __restrict__ out)
{
  const int r = blockIdx.x, t = threadIdx.x;
  float4 v = ((const float4*)(in + (size_t)r * D_))[t];
  float ss = blocksum256(v.x*v.x + v.y*v.y + v.z*v.z + v.w*v.w);
  float rs = rsqrtf(ss / (float)D_ + EPSF);
  const float4 w4 = ((const float4*)w)[t];
  bf4 o = { (__bf16)(v.x*rs*w4.x), (__bf16)(v.y*rs*w4.y),
            (__bf16)(v.z*rs*w4.z), (__bf16)(v.w*rs*w4.w) };
  ((bf4*)(out + (size_t)r * D_))[t] = o;
}

// ---------------- dwconv helper (strided buffer) ----------------
__device__ __forceinline__ float conv3s(const float* buf, int tok, int s, int ld, int col,
                                        const float* w, int C, int c){
  const float* p0 = buf + (size_t)tok * ld + col;
  float a  = (s >= 2) ? p0[-2*ld] : 0.f;
  float bb = (s >= 1) ? p0[-ld]   : 0.f;
  return w[c]*a + w[C + c]*bb + w[2*C + c]*p0[0];
}

// ---------------- QKV prep: dwconv + head-rmsnorm + RoPE + q_gain -> bf16 ----------------
__global__ __launch_bounds__(1024) void k_prep(
    const float* __restrict__ qkv,
    const float* __restrict__ qcw, const float* __restrict__ kcw, const float* __restrict__ vcw,
    const float* __restrict__ qgain,
    __bf16* __restrict__ q2, __bf16* __restrict__ k2, __bf16* __restrict__ v2)
{
  const int tok = blockIdx.x;
  const int s = tok & (S_ - 1);
  const int t = threadIdx.x, lane = t & 63;
  __shared__ float qsh[1024];

  const int j = lane & 31;
  float freq = expf(-(float)j * (9.210340371976184f / 32.f));
  float sn, cs;
  sincosf((float)s * freq, &sn, &cs);

  // ---- q (cols 0..1023 of qkv) ----
  float qc = conv3s(qkv, tok, s, 1536, t, qcw, D_, t);
  float ssq = wsum(qc * qc);
  float qn = qc * rsqrtf(ssq / 64.f + EPSF);
  float pr = __shfl_xor(qn, 32, 64);
  float qr = qn * cs + ((lane < 32) ? pr * sn : -pr * sn);
  qsh[t] = qr;
  __syncthreads();
  const int h = t >> 6, hd = lane;
  float accq = 0.f;
#pragma unroll
  for (int g = 0; g < 16; ++g) accq += qgain[h*16 + g] * qsh[g*64 + hd];
  q2[(size_t)tok * D_ + t] = (__bf16)accq;

  if (t < 256) {
    // ---- k (cols 1024..1279) ----
    float kc = conv3s(qkv, tok, s, 1536, 1024 + t, kcw, KV_, t);
    float ssk = wsum(kc * kc);
    float kn = kc * rsqrtf(ssk / 64.f + EPSF);
    float pk = __shfl_xor(kn, 32, 64);
    float kr = kn * cs + ((lane < 32) ? pk * sn : -pk * sn);
    k2[(size_t)tok * KV_ + t] = (__bf16)kr;
  } else if (t < 512) {
    // ---- v (cols 1280..1535) ----
    int c = t - 256;
    v2[(size_t)tok * KV_ + c] = (__bf16)conv3s(qkv, tok, s, 1536, 1280 + c, vcw, KV_, c);
  }
}

// ---------------- MFMA flash attention (bf16 compute, f32 accumulate) ----------------
#define LDK 72
__global__ __launch_bounds__(256) void k_attn(
    const __bf16* __restrict__ q2, const __bf16* __restrict__ k2,
    const __bf16* __restrict__ v2, float* __restrict__ y)
{
  __shared__ __attribute__((aligned(16))) __bf16 Ks[64*LDK];
  __shared__ __attribute__((aligned(16))) __bf16 Vt[64*LDK];
  __shared__ __attribute__((aligned(16))) __bf16 Ps[4][16*LDK];

  const int id = blockIdx.x;
  const int qb = id & 15;
  const int h  = (id >> 4) & 15;
  const int b  = id >> 8;
  const int tid = threadIdx.x, l = tid & 63, wq = tid >> 6;
  const int g = l >> 4, fr = l & 15;
  const int kvh = h >> 2;
  const int qrow = qb*64 + wq*16 + fr;

  bf8 qf[2];
#pragma unroll
  for (int ks = 0; ks < 2; ++ks)
    qf[ks] = *(const bf8*)&q2[(size_t)(b*S_ + qrow)*D_ + h*64 + g*8 + ks*32];

  float m = -1e30f, lsum = 0.f;
  f4 acc[4] = {};

  const int nch = qb + 1;
  for (int ch = 0; ch < nch; ++ch) {
    const int t0 = ch << 6;
    __syncthreads();
#pragma unroll
    for (int it = 0; it < 2; ++it) {
      int i = tid + it*256;
      int row = i >> 3, seg = (i & 7) << 3;
      *(bf8*)&Ks[row*LDK + seg] =
        *(const bf8*)&k2[(size_t)(b*S_ + t0 + row)*KV_ + kvh*64 + seg];
    }
    {
      int key4 = (tid & 15) << 2, hd4 = (tid >> 4) << 2;
      bf4 vv[4];
#pragma unroll
      for (int kk = 0; kk < 4; ++kk)
        vv[kk] = *(const bf4*)&v2[(size_t)(b*S_ + t0 + key4 + kk)*KV_ + kvh*64 + hd4];
#pragma unroll
      for (int hh = 0; hh < 4; ++hh) {
        bf4 w = { vv[0][hh], vv[1][hh], vv[2][hh], vv[3][hh] };
        *(bf4*)&Vt[(hd4 + hh)*LDK + key4] = w;
      }
    }
    __syncthreads();

    f4 sc[4] = {};
#pragma unroll
    for (int ks = 0; ks < 2; ++ks)
#pragma unroll
      for (int t = 0; t < 4; ++t) {
        bf8 kf = *(const bf8*)&Ks[(t*16 + fr)*LDK + g*8 + ks*32];
        sc[t] = __builtin_amdgcn_mfma_f32_16x16x32_bf16(kf, qf[ks], sc[t], 0, 0, 0);
      }

    const bool lastch = (ch == qb);
    float s[4][4];
    float pmax = -1e30f;
#pragma unroll
    for (int t = 0; t < 4; ++t)
#pragma unroll
      for (int r = 0; r < 4; ++r) {
        float v = sc[t][r] * 0.125f;
        if (lastch && (t0 + t*16 + g*4 + r > qrow)) v = -1e30f;
        s[t][r] = v;
        pmax = fmaxf(pmax, v);
      }
    pmax = fmaxf(pmax, __shfl_xor(pmax, 16, 64));
    pmax = fmaxf(pmax, __shfl_xor(pmax, 32, 64));
    float mnew = fmaxf(m, pmax);
    float alpha = __expf(m - mnew);
    float rs = 0.f;
#pragma unroll
    for (int t = 0; t < 4; ++t)
#pragma unroll
      for (int r = 0; r < 4; ++r) { float p = __expf(s[t][r] - mnew); s[t][r] = p; rs += p; }
    rs += __shfl_xor(rs, 16, 64);
    rs += __shfl_xor(rs, 32, 64);
    lsum = lsum * alpha + rs;
    m = mnew;
#pragma unroll
    for (int t = 0; t < 4; ++t) acc[t] = acc[t] * alpha;

#pragma unroll
    for (int t = 0; t < 4; ++t) {
      bf4 pw = { (__bf16)s[t][0], (__bf16)s[t][1], (__bf16)s[t][2], (__bf16)s[t][3] };
      *(bf4*)&Ps[wq][fr*LDK + t*16 + g*4] = pw;
    }

#pragma unroll
    for (int ks = 0; ks < 2; ++ks) {
      bf8 pf = *(const bf8*)&Ps[wq][fr*LDK + g*8 + ks*32];
#pragma unroll
      for (int t = 0; t < 4; ++t) {
        bf8 vf = *(const bf8*)&Vt[(t*16 + fr)*LDK + g*8 + ks*32];
        acc[t] = __builtin_amdgcn_mfma_f32_16x16x32_bf16(vf, pf, acc[t], 0, 0, 0);
      }
    }
  }

  float inv = 1.f / lsum;
#pragma unroll
  for (int t = 0; t < 4; ++t)
#pragma unroll
    for (int r = 0; r < 4; ++r)
      y[(size_t)(b*S_ + qrow)*D_ + h*64 + t*16 + g*4 + r] = acc[t][r] * inv;
}

// ---------------- elementwise ----------------
__global__ void k_addscale(float* __restrict__ x, const float* __restrict__ t,
                           const float* __restrict__ sc, float* __restrict__ sk)
{
  int i = blockIdx.x * 256 + threadIdx.x;
  int c4 = i & 255;
  float4 xv = ((float4*)x)[i];
  float4 tv = ((const float4*)t)[i];
  float4 s  = ((const float4*)sc)[c4];
  xv.x += s.x * tv.x; xv.y += s.y * tv.y; xv.z += s.z * tv.z; xv.w += s.w * tv.w;
  ((float4*)x)[i] = xv;
  if (sk) ((float4*)sk)[i] = xv;
}

__global__ void k_skipadd(float* __restrict__ x, const float* __restrict__ sk,
                          const float* __restrict__ sw, const float* __restrict__ sg)
{
  int i = blockIdx.x * 256 + threadIdx.x;
  int c4 = i & 255;
  float4 xv = ((float4*)x)[i];
  float4 sv = ((const float4*)sk)[i];
  float4 w = ((const float4*)sw)[c4];
  float4 g = ((const float4*)sg)[c4];
  xv.x += w.x / (1.f + __expf(-g.x)) * sv.x;
  xv.y += w.y / (1.f + __expf(-g.y)) * sv.y;
  xv.z += w.z / (1.f + __expf(-g.z)) * sv.z;
  xv.w += w.w / (1.f + __expf(-g.w)) * sv.w;
  ((float4*)x)[i] = xv;
}

// ---------------- fused silu*mul + dwconv + rmsnorm -> bf16 (padded to HIDP) ----------------
__device__ __forceinline__ float hprod(const float* row, int c){
  float a = row[c], b = row[HID_ + c];
  return a * b / (1.f + __expf(-b));
}
__global__ __launch_bounds__(256) void k_hfuse(
    const float* __restrict__ hb, const float* __restrict__ cw,
    const float* __restrict__ nw, __bf16* __restrict__ out)
{
  const int tok = blockIdx.x, t = threadIdx.x;
  const int s = tok & (S_ - 1);
  const float* row0 = hb + (size_t)tok * 5472;
  float v[11]; float ss = 0.f;
#pragma unroll
  for (int ii = 0; ii < 11; ++ii) {
    int c = t + ii*256;
    float cv = 0.f;
    if (c < HID_) {
      float p0 = hprod(row0, c);
      float p1 = (s >= 1) ? hprod(row0 - 5472, c) : 0.f;
      float p2 = (s >= 2) ? hprod(row0 - 2*5472, c) : 0.f;
      cv = cw[c]*p2 + cw[HID_ + c]*p1 + cw[2*HID_ + c]*p0;
    }
    v[ii] = cv; ss += cv*cv;
  }
  ss = blocksum256(ss);
  float rs = rsqrtf(ss / (float)HID_ + EPSF);
#pragma unroll
  for (int ii = 0; ii < 11; ++ii) {
    int c = t + ii*256;
    if (c < HIDP)
      out[(size_t)tok * HIDP + c] = (c < HID_) ? (__bf16)(v[ii]*rs*nw[c]) : (__bf16)0.f;
  }
}

// ---------------- bigram gate + final epilogue ----------------
__global__ void k_gate(const __bf16* __restrict__ xf, const float* __restrict__ bg,
                       float* __restrict__ gateb)
{
  int r = blockIdx.x * 4 + (threadIdx.x >> 6);
  int lane = threadIdx.x & 63;
  const __bf16* src = xf + (size_t)r * D_;
  float s = 0.f;
#pragma unroll
  for (int c = lane; c < D_; c += 64) s += (float)src[c] * bg[c];
  s = wsum(s);
  if (lane == 0) gateb[r] = 1.f / (1.f + __expf(-s));
}

__global__ void k_final(float* __restrict__ logits, const int* __restrict__ idx,
                        const float* __restrict__ gateb, const float* __restrict__ bh,
                        const float* __restrict__ bsc, const float* __restrict__ ub)
{
  int i = blockIdx.x * 256 + threadIdx.x;
  int row = i >> 11;
  int v4 = i & 2047;
  float4 lg = ((float4*)logits)[i];
  float g = gateb[row];
  int tok = idx[row];
  float4 bhv = ((const float4*)(bh + (size_t)tok * V_))[v4];
  float4 bsv = ((const float4*)bsc)[v4];
  float4 ubv = ((const float4*)ub)[v4];
  lg.x = SOFTCAPF * tanhf((lg.x + ubv.x + g * bhv.x * bsv.x) / SOFTCAPF);
  lg.y = SOFTCAPF * tanhf((lg.y + ubv.y + g * bhv.y * bsv.y) / SOFTCAPF);
  lg.z = SOFTCAPF * tanhf((lg.z + ubv.z + g * bhv.z * bsv.z) / SOFTCAPF);
  lg.w = SOFTCAPF * tanhf((lg.w + ubv.w + g * bhv.w * bsv.w) / SOFTCAPF);
  ((float4*)logits)[i] = lg;
}

// ---------------- host ----------------
static inline void gemm(const __bf16* A, const __bf16* W, float* C, int M, int N, int K,
                        int lda, hipStream_t s)
{
  int mt = M >> 7, nt = (N + 127) >> 7;
  k_gemm<<<dim3(mt * nt), dim3(256), 0, s>>>(A, W, C, M, N, K, lda, mt);
}

extern "C" void kernel_launch(void* const* d_in, const int* in_sizes, int n_in,
                              void* d_out, int out_size, void* d_ws, size_t ws_size,
                              hipStream_t stream)
{
  const int*   idx    = (const int*)d_in[0];
  const float* temb   = (const float*)d_in[1];
  const float* enw    = (const float*)d_in[2];
  const float* rmix   = (const float*)d_in[3];
  const float* anw    = (const float*)d_in[4];
  const float* mnw    = (const float*)d_in[5];
  const float* ascale = (const float*)d_in[6];
  const float* mscale = (const float*)d_in[7];
  const float* Wq     = (const float*)d_in[8];
  const float* Wk     = (const float*)d_in[9];
  const float* Wv     = (const float*)d_in[10];
  const float* qcw    = (const float*)d_in[11];
  const float* kcw    = (const float*)d_in[12];
  const float* vcw    = (const float*)d_in[13];
  const float* qgain  = (const float*)d_in[14];
  const float* panw   = (const float*)d_in[15];
  const float* Wo     = (const float*)d_in[16];
  const float* Wfc    = (const float*)d_in[17];
  const float* Wgate  = (const float*)d_in[18];
  const float* hcw    = (const float*)d_in[19];
  const float* hnw    = (const float*)d_in[20];
  const float* Wmp    = (const float*)d_in[21];
  const float* skw    = (const float*)d_in[22];
  const float* skg    = (const float*)d_in[23];
  const float* fnw    = (const float*)d_in[24];
  const float* lmw    = (const float*)d_in[25];
  const float* bh     = (const float*)d_in[26];
  const float* bsc    = (const float*)d_in[27];
  const float* bg     = (const float*)d_in[28];
  const float* ub     = (const float*)d_in[29];

  float* p = (float*)d_ws;
  float* x    = p; p += (size_t)NT_ * D_;
  float* x0   = p; p += (size_t)NT_ * D_;
  float* qkv  = p; p += (size_t)NT_ * 1536;
  float* y    = p; p += (size_t)NT_ * D_;
  float* t1   = p; p += (size_t)NT_ * D_;
  float* hb   = p; p += (size_t)NT_ * 5472;
  float* skips= p; p += (size_t)4 * NT_ * D_;
  float* gateb= p; p += NT_;
  __bf16* xnb = (__bf16*)p; p += (size_t)NT_ * D_ / 2;
  __bf16* q2b = (__bf16*)p; p += (size_t)NT_ * D_ / 2;
  __bf16* k2b = (__bf16*)p; p += (size_t)NT_ * KV_ / 2;
  __bf16* v2b = (__bf16*)p; p += (size_t)NT_ * KV_ / 2;
  __bf16* hnb = (__bf16*)p; p += (size_t)NT_ * HIDP / 2;
  __bf16* wqkv= (__bf16*)p; p += (size_t)L_ * 1536 * 1024 / 2;
  __bf16* wob = (__bf16*)p; p += (size_t)L_ * 1024 * 1024 / 2;
  __bf16* wfcg= (__bf16*)p; p += (size_t)L_ * 5472 * 1024 / 2;
  __bf16* wmpb= (__bf16*)p; p += (size_t)L_ * 1024 * HIDP / 2;
  __bf16* wlmb= (__bf16*)p; p += (size_t)V_ * 1024 / 2;
  float* logits = (float*)d_out;

  // ---- weight conversions (every launch; deterministic) ----
  auto cvt = [&](const float* s, __bf16* d, int perL, int K, int Kpad,
                 long dstL, long dstOff, int nl) {
    long nd4 = (long)nl * perL * (Kpad >> 2);
    int grid = (int)((nd4 + 255) / 256);
    k_cvt<<<grid, 256, 0, stream>>>(s, d, perL, K, Kpad, dstL, dstOff, nd4);
  };
  cvt(Wq,    wqkv, 1024, 1024, 1024, 1536L*1024, 0,          L_);
  cvt(Wk,    wqkv,  256, 1024, 1024, 1536L*1024, 1024L*1024, L_);
  cvt(Wv,    wqkv,  256, 1024, 1024, 1536L*1024, 1280L*1024, L_);
  cvt(Wo,    wob,  1024, 1024, 1024, 1024L*1024, 0,          L_);
  cvt(Wfc,   wfcg, 2736, 1024, 1024, 5472L*1024, 0,          L_);
  cvt(Wgate, wfcg, 2736, 1024, 1024, 5472L*1024, 2736L*1024, L_);
  cvt(Wmp,   wmpb, 1024, 2736, HIDP, 1024L*HIDP, 0,          L_);
  cvt(lmw,   wlmb, 8192, 1024, 1024, 8192L*1024, 0,          1);

  const int g4 = NT_ * D_ / 1024;

  k_embed<<<NT_, 256, 0, stream>>>(idx, temb, enw, x, x0);

  for (int i = 0; i < L_; ++i) {
    if (i >= L_/2) {
      int j = i - L_/2;
      k_skipadd<<<g4, 256, 0, stream>>>(x, skips + (size_t)(3 - j) * NT_ * D_,
                                        skw + (size_t)j * D_, skg + (size_t)j * D_);
    }
    // attention
    k_mixnorm<<<NT_, 256, 0, stream>>>(x, x0, rmix + (size_t)i * 2 * D_,
                                       anw + (size_t)i * D_, xnb);
    gemm(xnb, wqkv + (size_t)i * 1536 * 1024, qkv, NT_, 1536, 1024, 1024, stream);
    k_prep<<<NT_, 1024, 0, stream>>>(qkv,
                                     qcw + (size_t)i * 3 * D_, kcw + (size_t)i * 3 * KV_,
                                     vcw + (size_t)i * 3 * KV_, qgain + (size_t)i * H_ * H_,
                                     q2b, k2b, v2b);
    k_attn<<<B_ * H_ * (S_/64), 256, 0, stream>>>(q2b, k2b, v2b, y);
    k_rmsnormb<<<NT_, 256, 0, stream>>>(y, panw + (size_t)i * D_, xnb);
    gemm(xnb, wob + (size_t)i * 1024 * 1024, t1, NT_, 1024, 1024, 1024, stream);
    k_addscale<<<g4, 256, 0, stream>>>(x, t1, ascale + (size_t)i * D_, nullptr);
    // mlp
    k_rmsnormb<<<NT_, 256, 0, stream>>>(x, mnw + (size_t)i * D_, xnb);
    gemm(xnb, wfcg + (size_t)i * 5472 * 1024, hb, NT_, 5472, 1024, 1024, stream);
    k_hfuse<<<NT_, 256, 0, stream>>>(hb, hcw + (size_t)i * 3 * HID_,
                                     hnw + (size_t)i * HID_, hnb);
    gemm(hnb, wmpb + (size_t)i * 1024 * HIDP, t1, NT_, 1024, HIDP, HIDP, stream);
    k_addscale<<<g4, 256, 0, stream>>>(x, t1, mscale + (size_t)i * D_,
                                       (i < L_/2) ? skips + (size_t)i * NT_ * D_ : nullptr);
  }

  k_rmsnormb<<<NT_, 256, 0, stream>>>(x, fnw, xnb);
  gemm(xnb, wlmb, logits, NT_, V_, 1024, 1024, stream);
  k_gate<<<NT_/4, 256, 0, stream>>>(xnb, bg, gateb);
  k_final<<<NT_ * V_ / 1024, 256, 0, stream>>>(logits, idx, gateb, bh, bsc, ub);
}

// Round 4
// 2247.563 us; speedup vs baseline: 3.3499x; 1.0765x over previous
//
#include <hip/hip_runtime.h>
#include <hip/hip_bf16.h>
#include <cstdint>
#include <cstddef>

#define B_   2
#define S_   1024
#define V_   8192
#define D_   1024
#define H_   16
#define KVH_ 4
#define L_   8
#define HD_  64
#define KV_  256
#define HID_ 2736
#define HIDP 2752
#define NT_  (B_*S_)
#define EPSF 1.1920928955078125e-7f
#define SOFTCAPF 30.0f

typedef __bf16 bf8 __attribute__((ext_vector_type(8)));
typedef __bf16 bf4 __attribute__((ext_vector_type(4)));
typedef float  f4  __attribute__((ext_vector_type(4)));

// async global->LDS, 16B per lane; dst is wave-uniform base + lane*16
#define GLDS16(g, l) __builtin_amdgcn_global_load_lds( \
    (const __attribute__((address_space(1))) void*)(g), \
    (__attribute__((address_space(3))) void*)(l), 16, 0, 0)

// ---------------- wave / block reductions ----------------
__device__ __forceinline__ float wsum(float v){
#pragma unroll
  for (int m = 32; m >= 1; m >>= 1) v += __shfl_xor(v, m, 64);
  return v;
}
__device__ __forceinline__ float blocksum256(float v){
  __shared__ float red[4];
  v = wsum(v);
  if ((threadIdx.x & 63) == 0) red[threadIdx.x >> 6] = v;
  __syncthreads();
  return red[0] + red[1] + red[2] + red[3];
}

// ---------------- GEMM: C[M,N] = A[M,K] @ W[N,K]^T (bf16 in, f32 out) ----------------
// m97 structure; BM templated (128 or 64), BN=128, BK=32, global_load_lds w=16.
// XOR swizzle applied on global source col-segment (write side) and ds_read (read side).
template<int BM, bool EPI>
__global__ __launch_bounds__(256) void k_gemm(
    const __bf16* __restrict__ A, const __bf16* __restrict__ Wt,
    float* __restrict__ C, int M, int N, int K, int lda, int mtiles,
    const int* __restrict__ idx, const float* __restrict__ gateb,
    const float* __restrict__ bhd, const float* __restrict__ bsc,
    const float* __restrict__ ub)
{
  __shared__ __attribute__((aligned(16))) __bf16 As[BM*32];
  __shared__ __attribute__((aligned(16))) __bf16 Bs[128*32];
  const int tid  = threadIdx.x;
  const int bm   = blockIdx.x % mtiles;
  const int bn   = blockIdx.x / mtiles;
  const int m0   = bm * BM, n0 = bn << 7;
  const int lane = tid & 63, wv = tid >> 6;
  const int wm   = (BM == 128) ? ((wv >> 1) << 6) : ((wv >> 1) << 5);
  const int wn   = (wv & 1) << 6;
  const int fr   = lane & 15, g = lane >> 4;
  constexpr int MI = BM / 32;          // acc rows per wave (4 or 2)

  f4 acc[MI][4] = {};

  const int r0 = lane >> 2;
  const int cs = (lane & 3) ^ (r0 & 3);          // swizzled 8-elem col segment
  // A staging: BM=128 -> 2 issues/wave (rows wv*32+r0, +16); BM=64 -> 1 issue (rows wv*16+r0)
  const __bf16* aq0 = A + (size_t)(m0 + ((BM == 128) ? wv*32 : wv*16) + r0) * lda + cs*8;
  const __bf16* aq1 = aq0 + (size_t)16 * lda;    // unused for BM=64
  int br0 = n0 + wv*32 + r0;      if (br0 > N-1) br0 = N-1;
  int br1 = n0 + wv*32 + r0 + 16; if (br1 > N-1) br1 = N-1;
  const __bf16* bq0 = Wt + (size_t)br0 * K + cs*8;
  const __bf16* bq1 = Wt + (size_t)br1 * K + cs*8;
  __bf16* al0 = As + ((BM == 128) ? wv*1024 : wv*512);
  __bf16* al1 = al0 + 512;
  __bf16* bl0 = Bs + wv*1024;  __bf16* bl1 = bl0 + 512;

  for (int k0 = 0; k0 < K; k0 += 32) {
    __syncthreads();
    GLDS16(aq0, al0);
    if (BM == 128) GLDS16(aq1, al1);
    GLDS16(bq0, bl0); GLDS16(bq1, bl1);
    aq0 += 32; bq0 += 32; bq1 += 32;
    if (BM == 128) aq1 += 32;
    __syncthreads();

    bf8 af[MI], bff[4];
#pragma unroll
    for (int i = 0; i < MI; ++i)
      af[i]  = *(const bf8*)&As[(wm + i*16 + fr) * 32 + ((g ^ (fr & 3)) << 3)];
#pragma unroll
    for (int j = 0; j < 4; ++j)
      bff[j] = *(const bf8*)&Bs[(wn + j*16 + fr) * 32 + ((g ^ (fr & 3)) << 3)];
#pragma unroll
    for (int i = 0; i < MI; ++i)
#pragma unroll
      for (int j = 0; j < 4; ++j)
        acc[i][j] = __builtin_amdgcn_mfma_f32_16x16x32_bf16(af[i], bff[j], acc[i][j], 0, 0, 0);
  }

  const int rbase = g << 2;
#pragma unroll
  for (int i = 0; i < MI; ++i) {
    int gm = m0 + wm + i*16 + rbase;
#pragma unroll
    for (int j = 0; j < 4; ++j) {
      int gn = n0 + wn + j*16 + fr;
      if (gn < N) {
        if (EPI) {
          float u = ub[gn], bs = bsc[gn];
#pragma unroll
          for (int r = 0; r < 4; ++r) {
            int row = gm + r;
            float val = acc[i][j][r] + u + gateb[row] * bhd[(size_t)idx[row]*V_ + gn] * bs;
            C[(size_t)row * N + gn] = SOFTCAPF * tanhf(val / SOFTCAPF);
          }
        } else {
#pragma unroll
          for (int r = 0; r < 4; ++r)
            C[(size_t)(gm + r) * N + gn] = acc[i][j][r];
        }
      }
    }
  }
}

// ---------------- weight f32 -> bf16 convert (with layer interleave + K pad) ----------------
__global__ void k_cvt(const float* __restrict__ s, __bf16* __restrict__ d,
                      int perL, int K, int Kpad, long dstL, long dstOff, long nd4)
{
  long i = (long)blockIdx.x * 256 + threadIdx.x;
  if (i >= nd4) return;
  const int kp4 = Kpad >> 2;
  long row = i / kp4;
  int  c   = (int)(i % kp4) << 2;
  long layer = row / perL, r = row % perL;
  bf4 o;
  if (c < K) {
    float4 v = *(const float4*)(s + (layer*perL + r) * (long)K + c);
    o[0] = (__bf16)v.x; o[1] = (__bf16)v.y; o[2] = (__bf16)v.z; o[3] = (__bf16)v.w;
  } else { o[0] = o[1] = o[2] = o[3] = (__bf16)0.f; }
  *(bf4*)(d + layer*dstL + dstOff + (long)r*Kpad + c) = o;
}

// ---------------- embedding + rmsnorm ----------------
__global__ void k_embed(const int* __restrict__ idx, const float* __restrict__ emb,
                        const float* __restrict__ wn, float* __restrict__ x, float* __restrict__ x0)
{
  const int r = blockIdx.x, t = threadIdx.x;
  const float4 v = ((const float4*)(emb + (size_t)idx[r] * D_))[t];
  float ss = blocksum256(v.x*v.x + v.y*v.y + v.z*v.z + v.w*v.w);
  float rs = rsqrtf(ss / (float)D_ + EPSF);
  const float4 w = ((const float4*)wn)[t];
  float4 o = make_float4(v.x*rs*w.x, v.y*rs*w.y, v.z*rs*w.z, v.w*rs*w.w);
  ((float4*)(x  + (size_t)r * D_))[t] = o;
  ((float4*)(x0 + (size_t)r * D_))[t] = o;
}

// ---------------- block start: [x += msc*t1] [skip store] [skip add] mix + norm ----------------
__global__ void k_blockstart(
    float* __restrict__ x, const float* __restrict__ x0,
    const float* __restrict__ t1, const float* __restrict__ msc,
    float* __restrict__ skstore, const float* __restrict__ skread, int same,
    const float* __restrict__ skw, const float* __restrict__ skg,
    const float* __restrict__ mix, const float* __restrict__ nw,
    __bf16* __restrict__ xn)
{
  const int r = blockIdx.x, t = threadIdx.x;
  const size_t i4 = (size_t)r * 256 + t;
  float4 xv = ((float4*)x)[i4];
  if (t1) {
    float4 tv = ((const float4*)t1)[i4];
    float4 s  = ((const float4*)msc)[t];
    xv.x += s.x*tv.x; xv.y += s.y*tv.y; xv.z += s.z*tv.z; xv.w += s.w*tv.w;
  }
  if (skstore) ((float4*)skstore)[i4] = xv;
  if (skw) {
    float4 sv;
    if (same) sv = xv;
    else      sv = ((const float4*)skread)[i4];
    float4 w = ((const float4*)skw)[t];
    float4 g = ((const float4*)skg)[t];
    xv.x += w.x / (1.f + __expf(-g.x)) * sv.x;
    xv.y += w.y / (1.f + __expf(-g.y)) * sv.y;
    xv.z += w.z / (1.f + __expf(-g.z)) * sv.z;
    xv.w += w.w / (1.f + __expf(-g.w)) * sv.w;
  }
  float4 x0v = ((const float4*)x0)[i4];
  float4 m0  = ((const float4*)mix)[t];
  float4 m1  = ((const float4*)(mix + D_))[t];
  float4 nv;
  nv.x = m0.x*xv.x + m1.x*x0v.x; nv.y = m0.y*xv.y + m1.y*x0v.y;
  nv.z = m0.z*xv.z + m1.z*x0v.z; nv.w = m0.w*xv.w + m1.w*x0v.w;
  ((float4*)x)[i4] = nv;
  float ss = blocksum256(nv.x*nv.x + nv.y*nv.y + nv.z*nv.z + nv.w*nv.w);
  float rs = rsqrtf(ss / (float)D_ + EPSF);
  const float4 w = ((const float4*)nw)[t];
  bf4 o = { (__bf16)(nv.x*rs*w.x), (__bf16)(nv.y*rs*w.y),
            (__bf16)(nv.z*rs*w.z), (__bf16)(nv.w*rs*w.w) };
  ((bf4*)xn)[i4] = o;
}

// ---------------- x += sc*t1 ; xn = bf16(rmsnorm(x)*nw) ----------------
__global__ void k_addnorm(float* __restrict__ x, const float* __restrict__ t1,
                          const float* __restrict__ sc, const float* __restrict__ nw,
                          __bf16* __restrict__ xn)
{
  const int r = blockIdx.x, t = threadIdx.x;
  const size_t i4 = (size_t)r * 256 + t;
  float4 xv = ((float4*)x)[i4];
  float4 tv = ((const float4*)t1)[i4];
  float4 s  = ((const float4*)sc)[t];
  xv.x += s.x*tv.x; xv.y += s.y*tv.y; xv.z += s.z*tv.z; xv.w += s.w*tv.w;
  ((float4*)x)[i4] = xv;
  float ss = blocksum256(xv.x*xv.x + xv.y*xv.y + xv.z*xv.z + xv.w*xv.w);
  float rs = rsqrtf(ss / (float)D_ + EPSF);
  const float4 w = ((const float4*)nw)[t];
  bf4 o = { (__bf16)(xv.x*rs*w.x), (__bf16)(xv.y*rs*w.y),
            (__bf16)(xv.z*rs*w.z), (__bf16)(xv.w*rs*w.w) };
  ((bf4*)xn)[i4] = o;
}

// ---------------- rmsnorm D=1024, f32 in -> bf16 out ----------------
__global__ void k_rmsnormb(const float* __restrict__ in, const float* __restrict__ w,
                           __bf16* __restrict__ out)
{
  const int r = blockIdx.x, t = threadIdx.x;
  float4 v = ((const float4*)(in + (size_t)r * D_))[t];
  float ss = blocksum256(v.x*v.x + v.y*v.y + v.z*v.z + v.w*v.w);
  float rs = rsqrtf(ss / (float)D_ + EPSF);
  const float4 w4 = ((const float4*)w)[t];
  bf4 o = { (__bf16)(v.x*rs*w4.x), (__bf16)(v.y*rs*w4.y),
            (__bf16)(v.z*rs*w4.z), (__bf16)(v.w*rs*w4.w) };
  ((bf4*)(out + (size_t)r * D_))[t] = o;
}

// ---------------- dwconv helper (strided buffer) ----------------
__device__ __forceinline__ float conv3s(const float* buf, int tok, int s, int ld, int col,
                                        const float* w, int C, int c){
  const float* p0 = buf + (size_t)tok * ld + col;
  float a  = (s >= 2) ? p0[-2*ld] : 0.f;
  float bb = (s >= 1) ? p0[-ld]   : 0.f;
  return w[c]*a + w[C + c]*bb + w[2*C + c]*p0[0];
}

// ---------------- QKV prep: dwconv + head-rmsnorm + RoPE + q_gain -> bf16 ----------------
__global__ __launch_bounds__(1024) void k_prep(
    const float* __restrict__ qkv,
    const float* __restrict__ qcw, const float* __restrict__ kcw, const float* __restrict__ vcw,
    const float* __restrict__ qgain,
    __bf16* __restrict__ q2, __bf16* __restrict__ k2, __bf16* __restrict__ v2)
{
  const int tok = blockIdx.x;
  const int s = tok & (S_ - 1);
  const int t = threadIdx.x, lane = t & 63;
  __shared__ float qsh[1024];

  const int j = lane & 31;
  float freq = expf(-(float)j * (9.210340371976184f / 32.f));
  float sn, cs;
  sincosf((float)s * freq, &sn, &cs);

  float qc = conv3s(qkv, tok, s, 1536, t, qcw, D_, t);
  float ssq = wsum(qc * qc);
  float qn = qc * rsqrtf(ssq / 64.f + EPSF);
  float pr = __shfl_xor(qn, 32, 64);
  float qr = qn * cs + ((lane < 32) ? pr * sn : -pr * sn);
  qsh[t] = qr;
  __syncthreads();
  const int h = t >> 6, hd = lane;
  float accq = 0.f;
#pragma unroll
  for (int g = 0; g < 16; ++g) accq += qgain[h*16 + g] * qsh[g*64 + hd];
  q2[(size_t)tok * D_ + t] = (__bf16)accq;

  if (t < 256) {
    float kc = conv3s(qkv, tok, s, 1536, 1024 + t, kcw, KV_, t);
    float ssk = wsum(kc * kc);
    float kn = kc * rsqrtf(ssk / 64.f + EPSF);
    float pk = __shfl_xor(kn, 32, 64);
    float kr = kn * cs + ((lane < 32) ? pk * sn : -pk * sn);
    k2[(size_t)tok * KV_ + t] = (__bf16)kr;
  } else if (t < 512) {
    int c = t - 256;
    v2[(size_t)tok * KV_ + c] = (__bf16)conv3s(qkv, tok, s, 1536, 1280 + c, vcw, KV_, c);
  }
}

// ---------------- MFMA flash attention (bf16 compute, f32 accumulate) ----------------
#define LDK 72
__global__ __launch_bounds__(256) void k_attn(
    const __bf16* __restrict__ q2, const __bf16* __restrict__ k2,
    const __bf16* __restrict__ v2, float* __restrict__ y)
{
  __shared__ __attribute__((aligned(16))) __bf16 Ks[64*LDK];
  __shared__ __attribute__((aligned(16))) __bf16 Vt[64*LDK];
  __shared__ __attribute__((aligned(16))) __bf16 Ps[4][16*LDK];

  const int id = blockIdx.x;
  const int qb = id & 15;
  const int h  = (id >> 4) & 15;
  const int b  = id >> 8;
  const int tid = threadIdx.x, l = tid & 63, wq = tid >> 6;
  const int g = l >> 4, fr = l & 15;
  const int kvh = h >> 2;
  const int qrow = qb*64 + wq*16 + fr;

  bf8 qf[2];
#pragma unroll
  for (int ks = 0; ks < 2; ++ks)
    qf[ks] = *(const bf8*)&q2[(size_t)(b*S_ + qrow)*D_ + h*64 + g*8 + ks*32];

  float m = -1e30f, lsum = 0.f;
  f4 acc[4] = {};

  const int nch = qb + 1;
  for (int ch = 0; ch < nch; ++ch) {
    const int t0 = ch << 6;
    __syncthreads();
#pragma unroll
    for (int it = 0; it < 2; ++it) {
      int i = tid + it*256;
      int row = i >> 3, seg = (i & 7) << 3;
      *(bf8*)&Ks[row*LDK + seg] =
        *(const bf8*)&k2[(size_t)(b*S_ + t0 + row)*KV_ + kvh*64 + seg];
    }
    {
      int key4 = (tid & 15) << 2, hd4 = (tid >> 4) << 2;
      bf4 vv[4];
#pragma unroll
      for (int kk = 0; kk < 4; ++kk)
        vv[kk] = *(const bf4*)&v2[(size_t)(b*S_ + t0 + key4 + kk)*KV_ + kvh*64 + hd4];
#pragma unroll
      for (int hh = 0; hh < 4; ++hh) {
        bf4 w = { vv[0][hh], vv[1][hh], vv[2][hh], vv[3][hh] };
        *(bf4*)&Vt[(hd4 + hh)*LDK + key4] = w;
      }
    }
    __syncthreads();

    f4 sc[4] = {};
#pragma unroll
    for (int ks = 0; ks < 2; ++ks)
#pragma unroll
      for (int t = 0; t < 4; ++t) {
        bf8 kf = *(const bf8*)&Ks[(t*16 + fr)*LDK + g*8 + ks*32];
        sc[t] = __builtin_amdgcn_mfma_f32_16x16x32_bf16(kf, qf[ks], sc[t], 0, 0, 0);
      }

    const bool lastch = (ch == qb);
    float s[4][4];
    float pmax = -1e30f;
#pragma unroll
    for (int t = 0; t < 4; ++t)
#pragma unroll
      for (int r = 0; r < 4; ++r) {
        float v = sc[t][r] * 0.125f;
        if (lastch && (t0 + t*16 + g*4 + r > qrow)) v = -1e30f;
        s[t][r] = v;
        pmax = fmaxf(pmax, v);
      }
    pmax = fmaxf(pmax, __shfl_xor(pmax, 16, 64));
    pmax = fmaxf(pmax, __shfl_xor(pmax, 32, 64));
    float mnew = fmaxf(m, pmax);
    float alpha = __expf(m - mnew);
    float rs = 0.f;
#pragma unroll
    for (int t = 0; t < 4; ++t)
#pragma unroll
      for (int r = 0; r < 4; ++r) { float p = __expf(s[t][r] - mnew); s[t][r] = p; rs += p; }
    rs += __shfl_xor(rs, 16, 64);
    rs += __shfl_xor(rs, 32, 64);
    lsum = lsum * alpha + rs;
    m = mnew;
#pragma unroll
    for (int t = 0; t < 4; ++t) acc[t] = acc[t] * alpha;

#pragma unroll
    for (int t = 0; t < 4; ++t) {
      bf4 pw = { (__bf16)s[t][0], (__bf16)s[t][1], (__bf16)s[t][2], (__bf16)s[t][3] };
      *(bf4*)&Ps[wq][fr*LDK + t*16 + g*4] = pw;
    }

#pragma unroll
    for (int ks = 0; ks < 2; ++ks) {
      bf8 pf = *(const bf8*)&Ps[wq][fr*LDK + g*8 + ks*32];
#pragma unroll
      for (int t = 0; t < 4; ++t) {
        bf8 vf = *(const bf8*)&Vt[(t*16 + fr)*LDK + g*8 + ks*32];
        acc[t] = __builtin_amdgcn_mfma_f32_16x16x32_bf16(vf, pf, acc[t], 0, 0, 0);
      }
    }
  }

  float inv = 1.f / lsum;
#pragma unroll
  for (int t = 0; t < 4; ++t)
#pragma unroll
    for (int r = 0; r < 4; ++r)
      y[(size_t)(b*S_ + qrow)*D_ + h*64 + t*16 + g*4 + r] = acc[t][r] * inv;
}

// ---------------- fused silu*mul + dwconv + rmsnorm -> bf16 (padded to HIDP) ----------------
__device__ __forceinline__ float hprod(const float* row, int c){
  float a = row[c], b = row[HID_ + c];
  return a * b / (1.f + __expf(-b));
}
__global__ __launch_bounds__(256) void k_hfuse(
    const float* __restrict__ hb, const float* __restrict__ cw,
    const float* __restrict__ nw, __bf16* __restrict__ out)
{
  const int tok = blockIdx.x, t = threadIdx.x;
  const int s = tok & (S_ - 1);
  const float* row0 = hb + (size_t)tok * 5472;
  float v[11]; float ss = 0.f;
#pragma unroll
  for (int ii = 0; ii < 11; ++ii) {
    int c = t + ii*256;
    float cv = 0.f;
    if (c < HID_) {
      float p0 = hprod(row0, c);
      float p1 = (s >= 1) ? hprod(row0 - 5472, c) : 0.f;
      float p2 = (s >= 2) ? hprod(row0 - 2*5472, c) : 0.f;
      cv = cw[c]*p2 + cw[HID_ + c]*p1 + cw[2*HID_ + c]*p0;
    }
    v[ii] = cv; ss += cv*cv;
  }
  ss = blocksum256(ss);
  float rs = rsqrtf(ss / (float)HID_ + EPSF);
#pragma unroll
  for (int ii = 0; ii < 11; ++ii) {
    int c = t + ii*256;
    if (c < HIDP)
      out[(size_t)tok * HIDP + c] = (c < HID_) ? (__bf16)(v[ii]*rs*nw[c]) : (__bf16)0.f;
  }
}

// ---------------- bigram gate ----------------
__global__ void k_gate(const __bf16* __restrict__ xf, const float* __restrict__ bg,
                       float* __restrict__ gateb)
{
  int r = blockIdx.x * 4 + (threadIdx.x >> 6);
  int lane = threadIdx.x & 63;
  const __bf16* src = xf + (size_t)r * D_;
  float s = 0.f;
#pragma unroll
  for (int c = lane; c < D_; c += 64) s += (float)src[c] * bg[c];
  s = wsum(s);
  if (lane == 0) gateb[r] = 1.f / (1.f + __expf(-s));
}

// ---------------- host ----------------
template<int BM, bool EPI>
static inline void gemm(const __bf16* A, const __bf16* W, float* C, int M, int N, int K,
                        int lda, hipStream_t s,
                        const int* idx = nullptr, const float* gateb = nullptr,
                        const float* bhd = nullptr, const float* bsc = nullptr,
                        const float* ub = nullptr)
{
  int mt = M / BM, nt = (N + 127) >> 7;
  k_gemm<BM, EPI><<<dim3(mt * nt), dim3(256), 0, s>>>(A, W, C, M, N, K, lda, mt,
                                                      idx, gateb, bhd, bsc, ub);
}

extern "C" void kernel_launch(void* const* d_in, const int* in_sizes, int n_in,
                              void* d_out, int out_size, void* d_ws, size_t ws_size,
                              hipStream_t stream)
{
  const int*   idx    = (const int*)d_in[0];
  const float* temb   = (const float*)d_in[1];
  const float* enw    = (const float*)d_in[2];
  const float* rmix   = (const float*)d_in[3];
  const float* anw    = (const float*)d_in[4];
  const float* mnw    = (const float*)d_in[5];
  const float* ascale = (const float*)d_in[6];
  const float* mscale = (const float*)d_in[7];
  const float* Wq     = (const float*)d_in[8];
  const float* Wk     = (const float*)d_in[9];
  const float* Wv     = (const float*)d_in[10];
  const float* qcw    = (const float*)d_in[11];
  const float* kcw    = (const float*)d_in[12];
  const float* vcw    = (const float*)d_in[13];
  const float* qgain  = (const float*)d_in[14];
  const float* panw   = (const float*)d_in[15];
  const float* Wo     = (const float*)d_in[16];
  const float* Wfc    = (const float*)d_in[17];
  const float* Wgate  = (const float*)d_in[18];
  const float* hcw    = (const float*)d_in[19];
  const float* hnw    = (const float*)d_in[20];
  const float* Wmp    = (const float*)d_in[21];
  const float* skw    = (const float*)d_in[22];
  const float* skg    = (const float*)d_in[23];
  const float* fnw    = (const float*)d_in[24];
  const float* lmw    = (const float*)d_in[25];
  const float* bh     = (const float*)d_in[26];
  const float* bsc    = (const float*)d_in[27];
  const float* bg     = (const float*)d_in[28];
  const float* ub     = (const float*)d_in[29];

  float* p = (float*)d_ws;
  float* x    = p; p += (size_t)NT_ * D_;
  float* x0   = p; p += (size_t)NT_ * D_;
  float* qkv  = p; p += (size_t)NT_ * 1536;
  float* y    = p; p += (size_t)NT_ * D_;
  float* t1   = p; p += (size_t)NT_ * D_;
  float* hb   = p; p += (size_t)NT_ * 5472;
  float* skips= p; p += (size_t)4 * NT_ * D_;
  float* gateb= p; p += NT_;
  __bf16* xnb = (__bf16*)p; p += (size_t)NT_ * D_ / 2;
  __bf16* q2b = (__bf16*)p; p += (size_t)NT_ * D_ / 2;
  __bf16* k2b = (__bf16*)p; p += (size_t)NT_ * KV_ / 2;
  __bf16* v2b = (__bf16*)p; p += (size_t)NT_ * KV_ / 2;
  __bf16* hnb = (__bf16*)p; p += (size_t)NT_ * HIDP / 2;
  __bf16* wqkv= (__bf16*)p; p += (size_t)L_ * 1536 * 1024 / 2;
  __bf16* wob = (__bf16*)p; p += (size_t)L_ * 1024 * 1024 / 2;
  __bf16* wfcg= (__bf16*)p; p += (size_t)L_ * 5472 * 1024 / 2;
  __bf16* wmpb= (__bf16*)p; p += (size_t)L_ * 1024 * HIDP / 2;
  __bf16* wlmb= (__bf16*)p; p += (size_t)V_ * 1024 / 2;
  float* logits = (float*)d_out;

  // ---- weight conversions (every launch; deterministic) ----
  auto cvt = [&](const float* s, __bf16* d, int perL, int K, int Kpad,
                 long dstL, long dstOff, int nl) {
    long nd4 = (long)nl * perL * (Kpad >> 2);
    int grid = (int)((nd4 + 255) / 256);
    k_cvt<<<grid, 256, 0, stream>>>(s, d, perL, K, Kpad, dstL, dstOff, nd4);
  };
  cvt(Wq,    wqkv, 1024, 1024, 1024, 1536L*1024, 0,          L_);
  cvt(Wk,    wqkv,  256, 1024, 1024, 1536L*1024, 1024L*1024, L_);
  cvt(Wv,    wqkv,  256, 1024, 1024, 1536L*1024, 1280L*1024, L_);
  cvt(Wo,    wob,  1024, 1024, 1024, 1024L*1024, 0,          L_);
  cvt(Wfc,   wfcg, 2736, 1024, 1024, 5472L*1024, 0,          L_);
  cvt(Wgate, wfcg, 2736, 1024, 1024, 5472L*1024, 2736L*1024, L_);
  cvt(Wmp,   wmpb, 1024, 2736, HIDP, 1024L*HIDP, 0,          L_);
  cvt(lmw,   wlmb, 8192, 1024, 1024, 8192L*1024, 0,          1);

  k_embed<<<NT_, 256, 0, stream>>>(idx, temb, enw, x, x0);

  for (int i = 0; i < L_; ++i) {
    // fused: prev-mlp residual + skip store + skip add + resid mix + attn norm
    const float* pmsc = (i > 0) ? mscale + (size_t)(i-1) * D_ : nullptr;
    float* skst = (i >= 1 && i <= 4) ? skips + (size_t)(i-1) * NT_ * D_ : nullptr;
    const float* skrd = (i >= 4) ? skips + (size_t)(7-i) * NT_ * D_ : nullptr;
    const float* swp = (i >= 4) ? skw + (size_t)(i-4) * D_ : nullptr;
    const float* sgp = (i >= 4) ? skg + (size_t)(i-4) * D_ : nullptr;
    k_blockstart<<<NT_, 256, 0, stream>>>(x, x0, (i > 0) ? t1 : nullptr, pmsc,
                                          skst, skrd, (i == 4) ? 1 : 0, swp, sgp,
                                          rmix + (size_t)i * 2 * D_,
                                          anw + (size_t)i * D_, xnb);
    gemm<64, false>(xnb, wqkv + (size_t)i * 1536 * 1024, qkv, NT_, 1536, 1024, 1024, stream);
    k_prep<<<NT_, 1024, 0, stream>>>(qkv,
                                     qcw + (size_t)i * 3 * D_, kcw + (size_t)i * 3 * KV_,
                                     vcw + (size_t)i * 3 * KV_, qgain + (size_t)i * H_ * H_,
                                     q2b, k2b, v2b);
    k_attn<<<B_ * H_ * (S_/64), 256, 0, stream>>>(q2b, k2b, v2b, y);
    k_rmsnormb<<<NT_, 256, 0, stream>>>(y, panw + (size_t)i * D_, xnb);
    gemm<64, false>(xnb, wob + (size_t)i * 1024 * 1024, t1, NT_, 1024, 1024, 1024, stream);
    k_addnorm<<<NT_, 256, 0, stream>>>(x, t1, ascale + (size_t)i * D_,
                                       mnw + (size_t)i * D_, xnb);
    gemm<128, false>(xnb, wfcg + (size_t)i * 5472 * 1024, hb, NT_, 5472, 1024, 1024, stream);
    k_hfuse<<<NT_, 256, 0, stream>>>(hb, hcw + (size_t)i * 3 * HID_,
                                     hnw + (size_t)i * HID_, hnb);
    gemm<64, false>(hnb, wmpb + (size_t)i * 1024 * HIDP, t1, NT_, 1024, HIDP, HIDP, stream);
  }

  // final: mlp7 residual + final norm
  k_addnorm<<<NT_, 256, 0, stream>>>(x, t1, mscale + (size_t)7 * D_, fnw, xnb);
  k_gate<<<NT_/4, 256, 0, stream>>>(xnb, bg, gateb);
  gemm<128, true>(xnb, wlmb, logits, NT_, V_, 1024, 1024, stream, idx, gateb, bh, bsc, ub);
}

// Round 5
// 2183.777 us; speedup vs baseline: 3.4478x; 1.0292x over previous
//
#include <hip/hip_runtime.h>
#include <hip/hip_bf16.h>
#include <cstdint>
#include <cstddef>

#define B_   2
#define S_   1024
#define V_   8192
#define D_   1024
#define H_   16
#define KVH_ 4
#define L_   8
#define HD_  64
#define KV_  256
#define HID_ 2736
#define HIDP 2752
#define NT_  (B_*S_)
#define EPSF 1.1920928955078125e-7f
#define SOFTCAPF 30.0f

typedef __bf16 bf8 __attribute__((ext_vector_type(8)));
typedef __bf16 bf4 __attribute__((ext_vector_type(4)));
typedef float  f4  __attribute__((ext_vector_type(4)));

// async global->LDS, 16B per lane; dst is wave-uniform base + lane*16
#define GLDS16(g, l) __builtin_amdgcn_global_load_lds( \
    (const __attribute__((address_space(1))) void*)(g), \
    (__attribute__((address_space(3))) void*)(l), 16, 0, 0)

// ---------------- wave / block reductions ----------------
__device__ __forceinline__ float wsum(float v){
#pragma unroll
  for (int m = 32; m >= 1; m >>= 1) v += __shfl_xor(v, m, 64);
  return v;
}
__device__ __forceinline__ float blocksum256(float v){
  __shared__ float red[4];
  v = wsum(v);
  if ((threadIdx.x & 63) == 0) red[threadIdx.x >> 6] = v;
  __syncthreads();
  return red[0] + red[1] + red[2] + red[3];
}

// ---------------- GEMM: C[M,N] = A[M,K] @ W[N,K]^T (bf16 in, f32 out) ----------------
// 2-phase pipelined m97 structure: double-buffered LDS, global_load_lds w=16
// prefetched one K-step ahead, ONE raw s_barrier + counted vmcnt per K-step.
// XOR swizzle on global source col-segment (write side) and ds_read (read side).
template<int BM, bool EPI>
__global__ __launch_bounds__(256) void k_gemm(
    const __bf16* __restrict__ A, const __bf16* __restrict__ Wt,
    float* __restrict__ C, int M, int N, int K, int lda, int mtiles,
    const int* __restrict__ idx, const float* __restrict__ gateb,
    const float* __restrict__ bhd, const float* __restrict__ bsc,
    const float* __restrict__ ub)
{
  __shared__ __attribute__((aligned(16))) __bf16 As[2][BM*32];
  __shared__ __attribute__((aligned(16))) __bf16 Bs[2][128*32];
  const int tid  = threadIdx.x;
  // XCD-aware block swizzle (grid %8 == 0 for all our shapes -> bijective)
  const int nwg = gridDim.x;
  const int wg  = (blockIdx.x & 7) * (nwg >> 3) + (blockIdx.x >> 3);
  const int bm   = wg % mtiles;
  const int bn   = wg / mtiles;
  const int m0   = bm * BM, n0 = bn << 7;
  const int lane = tid & 63, wv = tid >> 6;
  const int wm   = (BM == 128) ? ((wv >> 1) << 6) : ((wv >> 1) << 5);
  const int wn   = (wv & 1) << 6;
  const int fr   = lane & 15, g = lane >> 4;
  constexpr int MI = BM / 32;          // acc rows per wave (4 or 2)

  f4 acc[MI][4] = {};

  const int r0 = lane >> 2;
  const int cs = (lane & 3) ^ (r0 & 3);          // swizzled 8-elem col segment
  const __bf16* aq0 = A + (size_t)(m0 + ((BM == 128) ? wv*32 : wv*16) + r0) * lda + cs*8;
  const __bf16* aq1 = aq0 + (size_t)16 * lda;    // unused for BM=64
  int br0 = n0 + wv*32 + r0;      if (br0 > N-1) br0 = N-1;
  int br1 = n0 + wv*32 + r0 + 16; if (br1 > N-1) br1 = N-1;
  const __bf16* bq0 = Wt + (size_t)br0 * K + cs*8;
  const __bf16* bq1 = Wt + (size_t)br1 * K + cs*8;
  const int aoff = (BM == 128) ? wv*1024 : wv*512;

  const int nk = K >> 5;

  // prologue: stage K-step 0 into buffer 0
  {
    GLDS16(aq0, &As[0][aoff]);
    if (BM == 128) GLDS16(aq1, &As[0][aoff + 512]);
    GLDS16(bq0, &Bs[0][wv*1024]);
    GLDS16(bq1, &Bs[0][wv*1024 + 512]);
  }

  for (int kk = 0; kk < nk; ++kk) {
    const int cur = kk & 1;
    asm volatile("s_waitcnt vmcnt(0)" ::: "memory");   // my stage of tile kk landed
    __builtin_amdgcn_s_barrier();                      // everyone's landed; prior reads done
    asm volatile("" ::: "memory");

    if (kk + 1 < nk) {                                 // prefetch tile kk+1 (other buffer)
      const int nxt = cur ^ 1;
      const int ko = (kk + 1) << 5;
      GLDS16(aq0 + ko, &As[nxt][aoff]);
      if (BM == 128) GLDS16(aq1 + ko, &As[nxt][aoff + 512]);
      GLDS16(bq0 + ko, &Bs[nxt][wv*1024]);
      GLDS16(bq1 + ko, &Bs[nxt][wv*1024 + 512]);
    }

    bf8 af[MI], bff[4];
#pragma unroll
    for (int i = 0; i < MI; ++i)
      af[i]  = *(const bf8*)&As[cur][(wm + i*16 + fr) * 32 + ((g ^ (fr & 3)) << 3)];
#pragma unroll
    for (int j = 0; j < 4; ++j)
      bff[j] = *(const bf8*)&Bs[cur][(wn + j*16 + fr) * 32 + ((g ^ (fr & 3)) << 3)];
#pragma unroll
    for (int i = 0; i < MI; ++i)
#pragma unroll
      for (int j = 0; j < 4; ++j)
        acc[i][j] = __builtin_amdgcn_mfma_f32_16x16x32_bf16(af[i], bff[j], acc[i][j], 0, 0, 0);
    asm volatile("" ::: "memory");
  }

  const int rbase = g << 2;
#pragma unroll
  for (int i = 0; i < MI; ++i) {
    int gm = m0 + wm + i*16 + rbase;
#pragma unroll
    for (int j = 0; j < 4; ++j) {
      int gn = n0 + wn + j*16 + fr;
      if (gn < N) {
        if (EPI) {
          float u = ub[gn], bs = bsc[gn];
#pragma unroll
          for (int r = 0; r < 4; ++r) {
            int row = gm + r;
            float val = acc[i][j][r] + u + gateb[row] * bhd[(size_t)idx[row]*V_ + gn] * bs;
            C[(size_t)row * N + gn] = SOFTCAPF * tanhf(val / SOFTCAPF);
          }
        } else {
#pragma unroll
          for (int r = 0; r < 4; ++r)
            C[(size_t)(gm + r) * N + gn] = acc[i][j][r];
        }
      }
    }
  }
}

// ---------------- weight f32 -> bf16 convert (with layer interleave + K pad) ----------------
__global__ void k_cvt(const float* __restrict__ s, __bf16* __restrict__ d,
                      int perL, int K, int Kpad, long dstL, long dstOff, long nd4)
{
  long i = (long)blockIdx.x * 256 + threadIdx.x;
  if (i >= nd4) return;
  const int kp4 = Kpad >> 2;
  long row = i / kp4;
  int  c   = (int)(i % kp4) << 2;
  long layer = row / perL, r = row % perL;
  bf4 o;
  if (c < K) {
    float4 v = *(const float4*)(s + (layer*perL + r) * (long)K + c);
    o[0] = (__bf16)v.x; o[1] = (__bf16)v.y; o[2] = (__bf16)v.z; o[3] = (__bf16)v.w;
  } else { o[0] = o[1] = o[2] = o[3] = (__bf16)0.f; }
  *(bf4*)(d + layer*dstL + dstOff + (long)r*Kpad + c) = o;
}

// ---------------- embedding + rmsnorm ----------------
__global__ void k_embed(const int* __restrict__ idx, const float* __restrict__ emb,
                        const float* __restrict__ wn, float* __restrict__ x, float* __restrict__ x0)
{
  const int r = blockIdx.x, t = threadIdx.x;
  const float4 v = ((const float4*)(emb + (size_t)idx[r] * D_))[t];
  float ss = blocksum256(v.x*v.x + v.y*v.y + v.z*v.z + v.w*v.w);
  float rs = rsqrtf(ss / (float)D_ + EPSF);
  const float4 w = ((const float4*)wn)[t];
  float4 o = make_float4(v.x*rs*w.x, v.y*rs*w.y, v.z*rs*w.z, v.w*rs*w.w);
  ((float4*)(x  + (size_t)r * D_))[t] = o;
  ((float4*)(x0 + (size_t)r * D_))[t] = o;
}

// ---------------- block start: [x += msc*t1] [skip store] [skip add] mix + norm ----------------
__global__ void k_blockstart(
    float* __restrict__ x, const float* __restrict__ x0,
    const float* __restrict__ t1, const float* __restrict__ msc,
    float* __restrict__ skstore, const float* __restrict__ skread, int same,
    const float* __restrict__ skw, const float* __restrict__ skg,
    const float* __restrict__ mix, const float* __restrict__ nw,
    __bf16* __restrict__ xn)
{
  const int r = blockIdx.x, t = threadIdx.x;
  const size_t i4 = (size_t)r * 256 + t;
  float4 xv = ((float4*)x)[i4];
  if (t1) {
    float4 tv = ((const float4*)t1)[i4];
    float4 s  = ((const float4*)msc)[t];
    xv.x += s.x*tv.x; xv.y += s.y*tv.y; xv.z += s.z*tv.z; xv.w += s.w*tv.w;
  }
  if (skstore) ((float4*)skstore)[i4] = xv;
  if (skw) {
    float4 sv;
    if (same) sv = xv;
    else      sv = ((const float4*)skread)[i4];
    float4 w = ((const float4*)skw)[t];
    float4 g = ((const float4*)skg)[t];
    xv.x += w.x / (1.f + __expf(-g.x)) * sv.x;
    xv.y += w.y / (1.f + __expf(-g.y)) * sv.y;
    xv.z += w.z / (1.f + __expf(-g.z)) * sv.z;
    xv.w += w.w / (1.f + __expf(-g.w)) * sv.w;
  }
  float4 x0v = ((const float4*)x0)[i4];
  float4 m0  = ((const float4*)mix)[t];
  float4 m1  = ((const float4*)(mix + D_))[t];
  float4 nv;
  nv.x = m0.x*xv.x + m1.x*x0v.x; nv.y = m0.y*xv.y + m1.y*x0v.y;
  nv.z = m0.z*xv.z + m1.z*x0v.z; nv.w = m0.w*xv.w + m1.w*x0v.w;
  ((float4*)x)[i4] = nv;
  float ss = blocksum256(nv.x*nv.x + nv.y*nv.y + nv.z*nv.z + nv.w*nv.w);
  float rs = rsqrtf(ss / (float)D_ + EPSF);
  const float4 w = ((const float4*)nw)[t];
  bf4 o = { (__bf16)(nv.x*rs*w.x), (__bf16)(nv.y*rs*w.y),
            (__bf16)(nv.z*rs*w.z), (__bf16)(nv.w*rs*w.w) };
  ((bf4*)xn)[i4] = o;
}

// ---------------- x += sc*t1 ; xn = bf16(rmsnorm(x)*nw) ----------------
__global__ void k_addnorm(float* __restrict__ x, const float* __restrict__ t1,
                          const float* __restrict__ sc, const float* __restrict__ nw,
                          __bf16* __restrict__ xn)
{
  const int r = blockIdx.x, t = threadIdx.x;
  const size_t i4 = (size_t)r * 256 + t;
  float4 xv = ((float4*)x)[i4];
  float4 tv = ((const float4*)t1)[i4];
  float4 s  = ((const float4*)sc)[t];
  xv.x += s.x*tv.x; xv.y += s.y*tv.y; xv.z += s.z*tv.z; xv.w += s.w*tv.w;
  ((float4*)x)[i4] = xv;
  float ss = blocksum256(xv.x*xv.x + xv.y*xv.y + xv.z*xv.z + xv.w*xv.w);
  float rs = rsqrtf(ss / (float)D_ + EPSF);
  const float4 w = ((const float4*)nw)[t];
  bf4 o = { (__bf16)(xv.x*rs*w.x), (__bf16)(xv.y*rs*w.y),
            (__bf16)(xv.z*rs*w.z), (__bf16)(xv.w*rs*w.w) };
  ((bf4*)xn)[i4] = o;
}

// ---------------- rmsnorm D=1024, f32 in -> bf16 out ----------------
__global__ void k_rmsnormb(const float* __restrict__ in, const float* __restrict__ w,
                           __bf16* __restrict__ out)
{
  const int r = blockIdx.x, t = threadIdx.x;
  float4 v = ((const float4*)(in + (size_t)r * D_))[t];
  float ss = blocksum256(v.x*v.x + v.y*v.y + v.z*v.z + v.w*v.w);
  float rs = rsqrtf(ss / (float)D_ + EPSF);
  const float4 w4 = ((const float4*)w)[t];
  bf4 o = { (__bf16)(v.x*rs*w4.x), (__bf16)(v.y*rs*w4.y),
            (__bf16)(v.z*rs*w4.z), (__bf16)(v.w*rs*w4.w) };
  ((bf4*)(out + (size_t)r * D_))[t] = o;
}

// ---------------- dwconv helper (strided buffer) ----------------
__device__ __forceinline__ float conv3s(const float* buf, int tok, int s, int ld, int col,
                                        const float* w, int C, int c){
  const float* p0 = buf + (size_t)tok * ld + col;
  float a  = (s >= 2) ? p0[-2*ld] : 0.f;
  float bb = (s >= 1) ? p0[-ld]   : 0.f;
  return w[c]*a + w[C + c]*bb + w[2*C + c]*p0[0];
}

// ---------------- QKV prep: dwconv + head-rmsnorm + RoPE + q_gain -> bf16 ----------------
__global__ __launch_bounds__(1024) void k_prep(
    const float* __restrict__ qkv,
    const float* __restrict__ qcw, const float* __restrict__ kcw, const float* __restrict__ vcw,
    const float* __restrict__ qgain,
    __bf16* __restrict__ q2, __bf16* __restrict__ k2, __bf16* __restrict__ v2)
{
  const int tok = blockIdx.x;
  const int s = tok & (S_ - 1);
  const int t = threadIdx.x, lane = t & 63;
  __shared__ float qsh[1024];

  const int j = lane & 31;
  float freq = expf(-(float)j * (9.210340371976184f / 32.f));
  float sn, cs;
  sincosf((float)s * freq, &sn, &cs);

  float qc = conv3s(qkv, tok, s, 1536, t, qcw, D_, t);
  float ssq = wsum(qc * qc);
  float qn = qc * rsqrtf(ssq / 64.f + EPSF);
  float pr = __shfl_xor(qn, 32, 64);
  float qr = qn * cs + ((lane < 32) ? pr * sn : -pr * sn);
  qsh[t] = qr;
  __syncthreads();
  const int h = t >> 6, hd = lane;
  float accq = 0.f;
#pragma unroll
  for (int g = 0; g < 16; ++g) accq += qgain[h*16 + g] * qsh[g*64 + hd];
  q2[(size_t)tok * D_ + t] = (__bf16)accq;

  if (t < 256) {
    float kc = conv3s(qkv, tok, s, 1536, 1024 + t, kcw, KV_, t);
    float ssk = wsum(kc * kc);
    float kn = kc * rsqrtf(ssk / 64.f + EPSF);
    float pk = __shfl_xor(kn, 32, 64);
    float kr = kn * cs + ((lane < 32) ? pk * sn : -pk * sn);
    k2[(size_t)tok * KV_ + t] = (__bf16)kr;
  } else if (t < 512) {
    int c = t - 256;
    v2[(size_t)tok * KV_ + c] = (__bf16)conv3s(qkv, tok, s, 1536, 1280 + c, vcw, KV_, c);
  }
}

// ---------------- MFMA flash attention (bf16 compute, f32 accumulate) ----------------
#define LDK 72
__global__ __launch_bounds__(256) void k_attn(
    const __bf16* __restrict__ q2, const __bf16* __restrict__ k2,
    const __bf16* __restrict__ v2, float* __restrict__ y)
{
  __shared__ __attribute__((aligned(16))) __bf16 Ks[64*LDK];
  __shared__ __attribute__((aligned(16))) __bf16 Vt[64*LDK];
  __shared__ __attribute__((aligned(16))) __bf16 Ps[4][16*LDK];

  const int id = blockIdx.x;
  const int qb = id & 15;
  const int h  = (id >> 4) & 15;
  const int b  = id >> 8;
  const int tid = threadIdx.x, l = tid & 63, wq = tid >> 6;
  const int g = l >> 4, fr = l & 15;
  const int kvh = h >> 2;
  const int qrow = qb*64 + wq*16 + fr;

  bf8 qf[2];
#pragma unroll
  for (int ks = 0; ks < 2; ++ks)
    qf[ks] = *(const bf8*)&q2[(size_t)(b*S_ + qrow)*D_ + h*64 + g*8 + ks*32];

  float m = -1e30f, lsum = 0.f;
  f4 acc[4] = {};

  const int nch = qb + 1;
  for (int ch = 0; ch < nch; ++ch) {
    const int t0 = ch << 6;
    __syncthreads();
#pragma unroll
    for (int it = 0; it < 2; ++it) {
      int i = tid + it*256;
      int row = i >> 3, seg = (i & 7) << 3;
      *(bf8*)&Ks[row*LDK + seg] =
        *(const bf8*)&k2[(size_t)(b*S_ + t0 + row)*KV_ + kvh*64 + seg];
    }
    {
      int key4 = (tid & 15) << 2, hd4 = (tid >> 4) << 2;
      bf4 vv[4];
#pragma unroll
      for (int kk = 0; kk < 4; ++kk)
        vv[kk] = *(const bf4*)&v2[(size_t)(b*S_ + t0 + key4 + kk)*KV_ + kvh*64 + hd4];
#pragma unroll
      for (int hh = 0; hh < 4; ++hh) {
        bf4 w = { vv[0][hh], vv[1][hh], vv[2][hh], vv[3][hh] };
        *(bf4*)&Vt[(hd4 + hh)*LDK + key4] = w;
      }
    }
    __syncthreads();

    f4 sc[4] = {};
#pragma unroll
    for (int ks = 0; ks < 2; ++ks)
#pragma unroll
      for (int t = 0; t < 4; ++t) {
        bf8 kf = *(const bf8*)&Ks[(t*16 + fr)*LDK + g*8 + ks*32];
        sc[t] = __builtin_amdgcn_mfma_f32_16x16x32_bf16(kf, qf[ks], sc[t], 0, 0, 0);
      }

    const bool lastch = (ch == qb);
    float s[4][4];
    float pmax = -1e30f;
#pragma unroll
    for (int t = 0; t < 4; ++t)
#pragma unroll
      for (int r = 0; r < 4; ++r) {
        float v = sc[t][r] * 0.125f;
        if (lastch && (t0 + t*16 + g*4 + r > qrow)) v = -1e30f;
        s[t][r] = v;
        pmax = fmaxf(pmax, v);
      }
    pmax = fmaxf(pmax, __shfl_xor(pmax, 16, 64));
    pmax = fmaxf(pmax, __shfl_xor(pmax, 32, 64));
    float mnew = fmaxf(m, pmax);
    float alpha = __expf(m - mnew);
    float rs = 0.f;
#pragma unroll
    for (int t = 0; t < 4; ++t)
#pragma unroll
      for (int r = 0; r < 4; ++r) { float p = __expf(s[t][r] - mnew); s[t][r] = p; rs += p; }
    rs += __shfl_xor(rs, 16, 64);
    rs += __shfl_xor(rs, 32, 64);
    lsum = lsum * alpha + rs;
    m = mnew;
#pragma unroll
    for (int t = 0; t < 4; ++t) acc[t] = acc[t] * alpha;

#pragma unroll
    for (int t = 0; t < 4; ++t) {
      bf4 pw = { (__bf16)s[t][0], (__bf16)s[t][1], (__bf16)s[t][2], (__bf16)s[t][3] };
      *(bf4*)&Ps[wq][fr*LDK + t*16 + g*4] = pw;
    }

#pragma unroll
    for (int ks = 0; ks < 2; ++ks) {
      bf8 pf = *(const bf8*)&Ps[wq][fr*LDK + g*8 + ks*32];
#pragma unroll
      for (int t = 0; t < 4; ++t) {
        bf8 vf = *(const bf8*)&Vt[(t*16 + fr)*LDK + g*8 + ks*32];
        acc[t] = __builtin_amdgcn_mfma_f32_16x16x32_bf16(vf, pf, acc[t], 0, 0, 0);
      }
    }
  }

  float inv = 1.f / lsum;
#pragma unroll
  for (int t = 0; t < 4; ++t)
#pragma unroll
    for (int r = 0; r < 4; ++r)
      y[(size_t)(b*S_ + qrow)*D_ + h*64 + t*16 + g*4 + r] = acc[t][r] * inv;
}

// ---------------- fused silu*mul + dwconv + rmsnorm -> bf16 (padded to HIDP) ----------------
__device__ __forceinline__ float hprod(const float* row, int c){
  float a = row[c], b = row[HID_ + c];
  return a * b / (1.f + __expf(-b));
}
__global__ __launch_bounds__(256) void k_hfuse(
    const float* __restrict__ hb, const float* __restrict__ cw,
    const float* __restrict__ nw, __bf16* __restrict__ out)
{
  const int tok = blockIdx.x, t = threadIdx.x;
  const int s = tok & (S_ - 1);
  const float* row0 = hb + (size_t)tok * 5472;
  float v[11]; float ss = 0.f;
#pragma unroll
  for (int ii = 0; ii < 11; ++ii) {
    int c = t + ii*256;
    float cv = 0.f;
    if (c < HID_) {
      float p0 = hprod(row0, c);
      float p1 = (s >= 1) ? hprod(row0 - 5472, c) : 0.f;
      float p2 = (s >= 2) ? hprod(row0 - 2*5472, c) : 0.f;
      cv = cw[c]*p2 + cw[HID_ + c]*p1 + cw[2*HID_ + c]*p0;
    }
    v[ii] = cv; ss += cv*cv;
  }
  ss = blocksum256(ss);
  float rs = rsqrtf(ss / (float)HID_ + EPSF);
#pragma unroll
  for (int ii = 0; ii < 11; ++ii) {
    int c = t + ii*256;
    if (c < HIDP)
      out[(size_t)tok * HIDP + c] = (c < HID_) ? (__bf16)(v[ii]*rs*nw[c]) : (__bf16)0.f;
  }
}

// ---------------- bigram gate ----------------
__global__ void k_gate(const __bf16* __restrict__ xf, const float* __restrict__ bg,
                       float* __restrict__ gateb)
{
  int r = blockIdx.x * 4 + (threadIdx.x >> 6);
  int lane = threadIdx.x & 63;
  const __bf16* src = xf + (size_t)r * D_;
  float s = 0.f;
#pragma unroll
  for (int c = lane; c < D_; c += 64) s += (float)src[c] * bg[c];
  s = wsum(s);
  if (lane == 0) gateb[r] = 1.f / (1.f + __expf(-s));
}

// ---------------- host ----------------
template<int BM, bool EPI>
static inline void gemm(const __bf16* A, const __bf16* W, float* C, int M, int N, int K,
                        int lda, hipStream_t s,
                        const int* idx = nullptr, const float* gateb = nullptr,
                        const float* bhd = nullptr, const float* bsc = nullptr,
                        const float* ub = nullptr)
{
  int mt = M / BM, nt = (N + 127) >> 7;
  k_gemm<BM, EPI><<<dim3(mt * nt), dim3(256), 0, s>>>(A, W, C, M, N, K, lda, mt,
                                                      idx, gateb, bhd, bsc, ub);
}

extern "C" void kernel_launch(void* const* d_in, const int* in_sizes, int n_in,
                              void* d_out, int out_size, void* d_ws, size_t ws_size,
                              hipStream_t stream)
{
  const int*   idx    = (const int*)d_in[0];
  const float* temb   = (const float*)d_in[1];
  const float* enw    = (const float*)d_in[2];
  const float* rmix   = (const float*)d_in[3];
  const float* anw    = (const float*)d_in[4];
  const float* mnw    = (const float*)d_in[5];
  const float* ascale = (const float*)d_in[6];
  const float* mscale = (const float*)d_in[7];
  const float* Wq     = (const float*)d_in[8];
  const float* Wk     = (const float*)d_in[9];
  const float* Wv     = (const float*)d_in[10];
  const float* qcw    = (const float*)d_in[11];
  const float* kcw    = (const float*)d_in[12];
  const float* vcw    = (const float*)d_in[13];
  const float* qgain  = (const float*)d_in[14];
  const float* panw   = (const float*)d_in[15];
  const float* Wo     = (const float*)d_in[16];
  const float* Wfc    = (const float*)d_in[17];
  const float* Wgate  = (const float*)d_in[18];
  const float* hcw    = (const float*)d_in[19];
  const float* hnw    = (const float*)d_in[20];
  const float* Wmp    = (const float*)d_in[21];
  const float* skw    = (const float*)d_in[22];
  const float* skg    = (const float*)d_in[23];
  const float* fnw    = (const float*)d_in[24];
  const float* lmw    = (const float*)d_in[25];
  const float* bh     = (const float*)d_in[26];
  const float* bsc    = (const float*)d_in[27];
  const float* bg     = (const float*)d_in[28];
  const float* ub     = (const float*)d_in[29];

  float* p = (float*)d_ws;
  float* x    = p; p += (size_t)NT_ * D_;
  float* x0   = p; p += (size_t)NT_ * D_;
  float* qkv  = p; p += (size_t)NT_ * 1536;
  float* y    = p; p += (size_t)NT_ * D_;
  float* t1   = p; p += (size_t)NT_ * D_;
  float* hb   = p; p += (size_t)NT_ * 5472;
  float* skips= p; p += (size_t)4 * NT_ * D_;
  float* gateb= p; p += NT_;
  __bf16* xnb = (__bf16*)p; p += (size_t)NT_ * D_ / 2;
  __bf16* q2b = (__bf16*)p; p += (size_t)NT_ * D_ / 2;
  __bf16* k2b = (__bf16*)p; p += (size_t)NT_ * KV_ / 2;
  __bf16* v2b = (__bf16*)p; p += (size_t)NT_ * KV_ / 2;
  __bf16* hnb = (__bf16*)p; p += (size_t)NT_ * HIDP / 2;
  __bf16* wqkv= (__bf16*)p; p += (size_t)L_ * 1536 * 1024 / 2;
  __bf16* wob = (__bf16*)p; p += (size_t)L_ * 1024 * 1024 / 2;
  __bf16* wfcg= (__bf16*)p; p += (size_t)L_ * 5472 * 1024 / 2;
  __bf16* wmpb= (__bf16*)p; p += (size_t)L_ * 1024 * HIDP / 2;
  __bf16* wlmb= (__bf16*)p; p += (size_t)V_ * 1024 / 2;
  float* logits = (float*)d_out;

  // ---- weight conversions (every launch; deterministic) ----
  auto cvt = [&](const float* s, __bf16* d, int perL, int K, int Kpad,
                 long dstL, long dstOff, int nl) {
    long nd4 = (long)nl * perL * (Kpad >> 2);
    int grid = (int)((nd4 + 255) / 256);
    k_cvt<<<grid, 256, 0, stream>>>(s, d, perL, K, Kpad, dstL, dstOff, nd4);
  };
  cvt(Wq,    wqkv, 1024, 1024, 1024, 1536L*1024, 0,          L_);
  cvt(Wk,    wqkv,  256, 1024, 1024, 1536L*1024, 1024L*1024, L_);
  cvt(Wv,    wqkv,  256, 1024, 1024, 1536L*1024, 1280L*1024, L_);
  cvt(Wo,    wob,  1024, 1024, 1024, 1024L*1024, 0,          L_);
  cvt(Wfc,   wfcg, 2736, 1024, 1024, 5472L*1024, 0,          L_);
  cvt(Wgate, wfcg, 2736, 1024, 1024, 5472L*1024, 2736L*1024, L_);
  cvt(Wmp,   wmpb, 1024, 2736, HIDP, 1024L*HIDP, 0,          L_);
  cvt(lmw,   wlmb, 8192, 1024, 1024, 8192L*1024, 0,          1);

  k_embed<<<NT_, 256, 0, stream>>>(idx, temb, enw, x, x0);

  for (int i = 0; i < L_; ++i) {
    // fused: prev-mlp residual + skip store + skip add + resid mix + attn norm
    const float* pmsc = (i > 0) ? mscale + (size_t)(i-1) * D_ : nullptr;
    float* skst = (i >= 1 && i <= 4) ? skips + (size_t)(i-1) * NT_ * D_ : nullptr;
    const float* skrd = (i >= 4) ? skips + (size_t)(7-i) * NT_ * D_ : nullptr;
    const float* swp = (i >= 4) ? skw + (size_t)(i-4) * D_ : nullptr;
    const float* sgp = (i >= 4) ? skg + (size_t)(i-4) * D_ : nullptr;
    k_blockstart<<<NT_, 256, 0, stream>>>(x, x0, (i > 0) ? t1 : nullptr, pmsc,
                                          skst, skrd, (i == 4) ? 1 : 0, swp, sgp,
                                          rmix + (size_t)i * 2 * D_,
                                          anw + (size_t)i * D_, xnb);
    gemm<64, false>(xnb, wqkv + (size_t)i * 1536 * 1024, qkv, NT_, 1536, 1024, 1024, stream);
    k_prep<<<NT_, 1024, 0, stream>>>(qkv,
                                     qcw + (size_t)i * 3 * D_, kcw + (size_t)i * 3 * KV_,
                                     vcw + (size_t)i * 3 * KV_, qgain + (size_t)i * H_ * H_,
                                     q2b, k2b, v2b);
    k_attn<<<B_ * H_ * (S_/64), 256, 0, stream>>>(q2b, k2b, v2b, y);
    k_rmsnormb<<<NT_, 256, 0, stream>>>(y, panw + (size_t)i * D_, xnb);
    gemm<64, false>(xnb, wob + (size_t)i * 1024 * 1024, t1, NT_, 1024, 1024, 1024, stream);
    k_addnorm<<<NT_, 256, 0, stream>>>(x, t1, ascale + (size_t)i * D_,
                                       mnw + (size_t)i * D_, xnb);
    gemm<128, false>(xnb, wfcg + (size_t)i * 5472 * 1024, hb, NT_, 5472, 1024, 1024, stream);
    k_hfuse<<<NT_, 256, 0, stream>>>(hb, hcw + (size_t)i * 3 * HID_,
                                     hnw + (size_t)i * HID_, hnb);
    gemm<64, false>(hnb, wmpb + (size_t)i * 1024 * HIDP, t1, NT_, 1024, HIDP, HIDP, stream);
  }

  // final: mlp7 residual + final norm
  k_addnorm<<<NT_, 256, 0, stream>>>(x, t1, mscale + (size_t)7 * D_, fnw, xnb);
  k_gate<<<NT_/4, 256, 0, stream>>>(xnb, bg, gateb);
  gemm<128, true>(xnb, wlmb, logits, NT_, V_, 1024, 1024, stream, idx, gateb, bh, bsc, ub);
}